// Round 4
// baseline (3838423.234 us; speedup 1.0000x reference)
//
#include <hip/hip_runtime.h>
#include <math.h>

// GridLSTM one-flag-per-cell dataflow, fused f16 weights. V=50000,E=300,H=128,L=32,B=8.
// 256 blocks x 256 threads. bid = c*32 + i (i = grid row, c = t-slice chunk 0..7).
// gates = WU@ho_up + WL@ho_left + (Pproj+b) + Hypproj + upok*bU + lfok*bL
// with WU/WL precomputed f16x2 on device, consumed via v_dot2_f32_f16.
//
// R4 sync design: XCD-local LEFT exchange through the shared per-XCD L2,
// de-risked from R3 (which crashed the container before benching):
//   - workspace repacked to EXACTLY the R1-proven 5.30 MB footprint
//     (R3's 5.42 MB may have overrun ws -> page fault).
//   - no inline-asm data path: L2-tier uses `volatile` loads/stores
//     (guaranteed L1-bypass; worst case they degenerate to the UC tier,
//     which is the proven-correct R2 behavior).
//   - runtime rowok check via s_getreg(HW_REG_XCC_ID) (m09-verified):
//     all 8 row-siblings on one XCD? else R2 UC fallback (G16-safe).
//   Producer: phase1 (rowok): volatile stores of left Ho/Co copies ->
//   wave-local vmcnt(0) (fast L2 acks) -> volatile flag WFL. phase2: UC
//   stores of up copies -> drain -> UC flag WFU. Left consumers unblock
//   before the slow UC drain begins. Up edges unchanged (cross-XCD -> UC).

typedef _Float16 h2 __attribute__((ext_vector_type(2)));

__device__ __forceinline__ h2 pk_f16(float a, float b) {
    return __builtin_bit_cast(h2, __builtin_amdgcn_cvt_pkrtz(a, b));
}

// ---------------- workspace layout (float words) — total 1,325,056 = R1-proven ----
#define HYP_OFF   0            // Hypproj [32 j][8 b][1024]            (atomic f32) 1MB
#define WP_OFF    262144       // fused wts packed h2 [1024 g][256]    (atomic u32) 1MB
#define B_OFF     524288       // bU[1024] | bL[1024]
#define INITF_OFF 526336       // InitF [p*4] (1024)
#define WFU_OFF   527360       // UC per-wave flags [((i*8+c)*4+w)*4] (4096)
#define WFL_OFF   531456       // L2 per-wave flags [((i*8+c)*4+w)*4] (4096)
#define XCD_OFF   535552       // per-block XCD id [bid*4] (1024)
#define HOU_OFF   536576       // Ho UC  u32 f16x2 [4][32][8][128] (512KB)
#define HOL_OFF   667648       // Ho L2  u32 f16x2 [4][32][8][128] (512KB)
#define COU_OFF   798720       // Co UC  f32 [4][32][8][256]       (1MB)
#define COL_OFF   1060864      // Co L2  f32 [4][32][8][256]       (1MB)
#define HOF_OFF   1323008      // final ho(31,31) f32 [8 b][256 t] (8KB)
// end = 1325056 floats = 5.30 MB (== R1's harness-verified footprint)

#define BASE 0xAAAAAAAAu

__device__ __forceinline__ float sigm(float x) { return 1.f / (1.f + __expf(-x)); }
__device__ __forceinline__ float tanh_fast(float x) { return 1.f - 2.f / (__expf(2.f * x) + 1.f); }

__device__ __forceinline__ unsigned ld_flag(const unsigned* p) {
    return __hip_atomic_load(p, __ATOMIC_RELAXED, __HIP_MEMORY_SCOPE_AGENT);
}
__device__ __forceinline__ void st_flag(unsigned* p, unsigned v) {
    __hip_atomic_store(p, v, __ATOMIC_RELAXED, __HIP_MEMORY_SCOPE_AGENT);
}
__device__ __forceinline__ float ld_f32(const float* p) {
    unsigned u = __hip_atomic_load((const unsigned*)p, __ATOMIC_RELAXED, __HIP_MEMORY_SCOPE_AGENT);
    return __uint_as_float(u);
}
__device__ __forceinline__ void st_f32(float* p, float v) {
    __hip_atomic_store((unsigned*)p, __float_as_uint(v), __ATOMIC_RELAXED, __HIP_MEMORY_SCOPE_AGENT);
}
__device__ __forceinline__ void st_u32(unsigned* p, unsigned v) {
    __hip_atomic_store(p, v, __ATOMIC_RELAXED, __HIP_MEMORY_SCOPE_AGENT);
}
__device__ __forceinline__ unsigned long long ld_u64(const unsigned long long* p) {
    return __hip_atomic_load(p, __ATOMIC_RELAXED, __HIP_MEMORY_SCOPE_AGENT);
}
__device__ __forceinline__ float2 ld_f32x2(const float* p) {   // 8B-aligned, UC
    unsigned long long u = ld_u64((const unsigned long long*)p);
    float2 r; r.x = __uint_as_float((unsigned)u); r.y = __uint_as_float((unsigned)(u >> 32));
    return r;
}
// ---- L2-tier (volatile => at least L1-bypass; same-XCD coherent via shared L2) ----
__device__ __forceinline__ unsigned ld_l2(const unsigned* p) {
    return *(const volatile unsigned*)p;
}
__device__ __forceinline__ void st_l2(unsigned* p, unsigned v) {
    *(volatile unsigned*)p = v;
}
__device__ __forceinline__ float2 ld_l2x2(const float* p) {    // 8B-aligned
    unsigned long long u = *(const volatile unsigned long long*)p;
    float2 r; r.x = __uint_as_float((unsigned)u); r.y = __uint_as_float((unsigned)(u >> 32));
    return r;
}
__device__ __forceinline__ void wait_ge(const unsigned* f, unsigned target) {
    long spins = 0;
    while ((ld_flag(f) - BASE) < target) {
        __builtin_amdgcn_s_sleep(1);
        if (++spins > (1L << 22)) break;   // failsafe: wrong answer > hang
    }
}
__device__ __forceinline__ void wait_ge_l2(const unsigned* f, unsigned target) {
    long spins = 0;
    while ((ld_l2(f) - BASE) < target) {
        __builtin_amdgcn_s_sleep(1);
        if (++spins > (1L << 22)) break;   // failsafe
    }
}
__device__ __forceinline__ void drain_vmem() {
    asm volatile("s_waitcnt vmcnt(0)" ::: "memory");
}
__device__ __forceinline__ unsigned xcc_id() {
    unsigned v;
    asm volatile("s_getreg_b32 %0, hwreg(HW_REG_XCC_ID)" : "=s"(v));
    return v & 0xFu;
}

__global__ void __launch_bounds__(256, 1) grid_lstm_kernel(
    const int* __restrict__ premise, const int* __restrict__ hypothesis,
    const float* __restrict__ emb,
    const float* __restrict__ W_ih, const float* __restrict__ b_ih,
    const float* __restrict__ W_hh, const float* __restrict__ b_hh,
    const float* __restrict__ W_ch, const float* __restrict__ b_ch,
    const float* __restrict__ W_cc, const float* __restrict__ b_cc,
    const float* __restrict__ W1, const float* __restrict__ b1,
    const float* __restrict__ W2, const float* __restrict__ b2,
    const float* __restrict__ W3, const float* __restrict__ b3,
    float* __restrict__ out, float* __restrict__ ws)
{
    __shared__ h2    hAB[2048];      // f16 [8 b][256 kk]: kk<128 up, kk>=128 left (8KB)
    __shared__ float sCo[2048];      // f32 co_side [8 b][256] (8KB)
    __shared__ float ppL[1024];      // Pproj slice [8 b][128 g], g=(a<<5)|s (4KB)
    __shared__ float red[8448];      // gate partials [256][33] / embs / MLP (33.8KB)
    __shared__ float red2[2304];     // c partials [256][9] (9.2KB)

    const int tid = threadIdx.x;
    const int bid = blockIdx.x;
    const int i   = bid & 31;       // grid row
    const int c   = bid >> 5;       // t-slice chunk

    float*    Hypproj = ws + HYP_OFF;
    unsigned* WP      = (unsigned*)(ws + WP_OFF);
    float*    BU      = ws + B_OFF;
    float*    BL      = ws + B_OFF + 1024;
    unsigned* InitF   = (unsigned*)(ws + INITF_OFF);
    unsigned* WFU     = (unsigned*)(ws + WFU_OFF);
    unsigned* WFL     = (unsigned*)(ws + WFL_OFF);
    unsigned* XCDA    = (unsigned*)(ws + XCD_OFF);
    unsigned* HoU     = (unsigned*)(ws + HOU_OFF);
    unsigned* HoL     = (unsigned*)(ws + HOL_OFF);
    float*    CoU     = ws + COU_OFF;
    float*    CoL     = ws + COL_OFF;
    float*    HoF     = ws + HOF_OFF;

    const int tq = tid & 31, ks = tid >> 5;   // GEMM K-split coords
    const int tl = tid & 31, bb = tid >> 5;   // elementwise coords (t_local, batch)
    const unsigned myxcd = xcc_id();

    // ================= Init A: Pproj (LDS) + Hypproj for this block's gate rows ====
    {
        float* embs = red;   // [2 sides][8][300] = 4800 floats
        for (int idx = tid; idx < 4800; idx += 256) {
            int side = idx / 2400, rem = idx - side * 2400;
            int b = rem / 300, e = rem - b * 300;
            const int* toks = side ? hypothesis : premise;
            embs[idx] = emb[(long)toks[b * 32 + i] * 300 + e];
        }
        __syncthreads();
        #pragma unroll 1
        for (int q = 0; q < 4; q++) {
            const int oo = tid + q * 256;
            const int b = oo >> 7, g = oo & 127;
            const int gr = (g >> 5) * 256 + c * 32 + (g & 31);   // t-sliced gate row
            float accP = b_ih[gr] + b_hh[gr];
            float accH = 0.f;
            const float* wp = W_ih + (long)gr * 600;
            const float* eP = embs + b * 300;
            const float* eH = embs + 2400 + b * 300;
            for (int e = 0; e < 300; e += 4) {
                float4 w1 = *(const float4*)(wp + e);
                float4 w2v = *(const float4*)(wp + 300 + e);
                float4 p4 = *(const float4*)(eP + e);
                float4 h4 = *(const float4*)(eH + e);
                accP += w1.x * p4.x + w1.y * p4.y + w1.z * p4.z + w1.w * p4.w;
                accH += w2v.x * h4.x + w2v.y * h4.y + w2v.z * h4.z + w2v.w * h4.w;
            }
            st_f32(&Hypproj[i * 8192 + b * 1024 + gr], accH);     // cross-block
            ppL[b * 128 + g] = accP;                              // block-local
        }
        __syncthreads();   // embs (red) free
    }

    // ================= Init B: fused weight rows [4*bid, 4*bid+4) =================
    {
        const int tr = tid >> 6, col = (tid & 63) * 4;
        const int r  = bid * 4 + tr;
        float u[4] = {0.f, 0.f, 0.f, 0.f}, l[4] = {0.f, 0.f, 0.f, 0.f};
        const float* whU = W_hh + (long)r * 256;
        const float* whL = whU + 128;
        for (int k = 0; k < 128; k++) {
            const float wu = whU[k], wl = whL[k];
            float4 wc = *(const float4*)(W_ch + (long)k * 256 + col);
            u[0] += wu * wc.x; u[1] += wu * wc.y; u[2] += wu * wc.z; u[3] += wu * wc.w;
            l[0] += wl * wc.x; l[1] += wl * wc.y; l[2] += wl * wc.z; l[3] += wl * wc.w;
        }
        unsigned* wrow = WP + (long)r * 256;
        st_u32(&wrow[col / 2],       __builtin_bit_cast(unsigned, __builtin_amdgcn_cvt_pkrtz(u[0], u[1])));
        st_u32(&wrow[col / 2 + 1],   __builtin_bit_cast(unsigned, __builtin_amdgcn_cvt_pkrtz(u[2], u[3])));
        st_u32(&wrow[128 + col / 2],     __builtin_bit_cast(unsigned, __builtin_amdgcn_cvt_pkrtz(l[0], l[1])));
        st_u32(&wrow[128 + col / 2 + 1], __builtin_bit_cast(unsigned, __builtin_amdgcn_cvt_pkrtz(l[2], l[3])));
        if ((tid & 63) == 0) {   // bias projections for this row
            float su = 0.f, sl = 0.f;
            for (int k = 0; k < 128; k++) { su += whU[k] * b_ch[k]; sl += whL[k] * b_ch[k]; }
            st_f32(&BU[r], su); st_f32(&BL[r], sl);
        }
        if (tid == 0) st_flag(&XCDA[bid * 4], BASE + 1u + myxcd);   // publish XCD id
    }
    drain_vmem();
    __syncthreads();
    if (tid == 0) st_flag(&InitF[bid * 4], BASE + 1u);

    // ---- wait ALL inits (covers every Hypproj row + weights + XCD ids) ----
    wait_ge(&InitF[tid * 4], 1u);
    // ---- row co-location check: all 8 siblings of row i on one XCD? ----
    int okv = 1;
    if (tid < 8) okv = (ld_flag(&XCDA[(tid * 32 + i) * 4]) == BASE + 1u + myxcd);
    const bool rowok = __syncthreads_and(okv) != 0;

    // ---- load fused weight slice -> registers (f16x2), W_cc slice (fp32) ----
    h2 w[4][32];                  // 128 VGPRs
    #pragma unroll
    for (int a = 0; a < 4; a++) {
        const unsigned* src = WP + (long)(a * 256 + c * 32 + tq) * 256 + ks * 32;
        #pragma unroll
        for (int m = 0; m < 16; m++) {
            unsigned long long u2 = ld_u64((const unsigned long long*)(src + m * 2));
            w[a][2 * m]     = __builtin_bit_cast(h2, (unsigned)u2);
            w[a][2 * m + 1] = __builtin_bit_cast(h2, (unsigned)(u2 >> 32));
        }
    }
    float4 w3[8];                 // 32 VGPRs: W_cc row (c&3)*32+tq, K-seg ks*32..+32
    {
        const float* wr = W_cc + (long)((c & 3) * 32 + tq) * 256 + ks * 32;
        #pragma unroll
        for (int m = 0; m < 8; m++) w3[m] = *(const float4*)(wr + m * 4);
    }
    float bUv[4], bLv[4];
    #pragma unroll
    for (int a = 0; a < 4; a++) {
        bUv[a] = ld_f32(&BU[a * 256 + c * 32 + tl]);
        bLv[a] = ld_f32(&BL[a * 256 + c * 32 + tl]);
    }

    // ================= Wavefront: row i walks j = 0..31 =================
    #pragma unroll 1
    for (int j = 0; j < 32; j++) {
        const bool upok = (i > 0), lfok = (j > 0);
        const bool cok  = (c < 4) ? upok : lfok;
        const int  jl   = lfok ? (j - 1) : 0;

        // ---- prefetch Hypproj for elementwise (independent, overlaps the spin) ----
        float hyv[4];
        #pragma unroll
        for (int a = 0; a < 4; a++)
            hyv[a] = ld_f32(&Hypproj[j * 8192 + bb * 1024 + a * 256 + c * 32 + tl]);

        // ---- fine-grained dependency wait: per-wave flags, tier by edge type ----
        // lanes 0..31 : up blocks (i-1, cc=tid>>2), wave tid&3, target j+1 (UC)
        // lanes 32..59: left siblings (i, cc != c), wave (tid-32)&3, target j (L2|UC)
        if (upok && tid < 32) {
            wait_ge(&WFU[(((i - 1) * 8 + (tid >> 2)) * 4 + (tid & 3)) * 4], (unsigned)(j + 1));
        } else if (lfok && tid >= 32 && tid < 60) {
            int s = tid - 32;
            int cc = s >> 2;
            cc += (cc >= c) ? 1 : 0;          // skip self (own stores drained already)
            const int fidx = ((i * 8 + cc) * 4 + (s & 3)) * 4;
            if (rowok) wait_ge_l2(&WFL[fidx], (unsigned)j);
            else       wait_ge(&WFU[fidx], (unsigned)j);
        }
        __syncthreads();

        // ---- one bulk load + LDS stage (flags imply visibility; no retries) ----
        const unsigned* HoUp  = HoU + (size_t)(((i - 1) & 3) * 32 + j) * 1024;
        const size_t    lslot = (size_t)((i & 3) * 32 + jl);
        const unsigned* HoLfL = HoL + lslot * 1024;   // L2 tier
        const unsigned* HoLfU = HoU + lslot * 1024;   // UC fallback
        const float*    CoUp  = CoU + (size_t)(((i - 1) & 3) * 32 + j) * 2048;
        const float*    CoLfL = CoL + lslot * 2048;
        const float*    CoLfU = CoU + lslot * 2048;
        #pragma unroll
        for (int r = 0; r < 4; r++) {
            const int idx = r * 256 + tid;           // 0..1023
            const int b = idx >> 7, kk = idx & 127;  // f16 pair (2kk, 2kk+1)
            unsigned u = upok ? ld_flag(HoUp + b * 128 + kk) : 0u;
            unsigned l = 0u;
            if (lfok)
                l = rowok ? ld_l2(HoLfL + b * 128 + kk)
                          : ld_flag(HoLfU + b * 128 + kk);
            float2 cv = make_float2(0.f, 0.f);
            if (cok) {
                if (c < 4)      cv = ld_f32x2(CoUp + b * 256 + 2 * kk);        // up, UC
                else if (rowok) cv = ld_l2x2(CoLfL + b * 256 + 2 * kk);        // left, L2
                else            cv = ld_f32x2(CoLfU + b * 256 + 2 * kk);       // left, UC
            }
            hAB[b * 256 + kk]       = __builtin_bit_cast(h2, u);   // 0u == f16 pair (0,0)
            hAB[b * 256 + 128 + kk] = __builtin_bit_cast(h2, l);
            sCo[b * 256 + 2 * kk] = cv.x; sCo[b * 256 + 2 * kk + 1] = cv.y;
        }
        __syncthreads();

        // ---- fused gates GEMM (f16 dot2) + c-path (fp32) ----
        float acc[4][8], a3[8];
        #pragma unroll
        for (int a = 0; a < 4; a++)
            #pragma unroll
            for (int b = 0; b < 8; b++) acc[a][b] = 0.f;
        #pragma unroll
        for (int b = 0; b < 8; b++) a3[b] = 0.f;
        #pragma unroll
        for (int b = 0; b < 8; b++) {
            const h2*    hb = hAB + b * 256 + ks * 32;
            const float* cb = sCo + b * 256 + ks * 32;
            #pragma unroll
            for (int m4 = 0; m4 < 8; m4++) {
                uint4 hu = *(const uint4*)(hb + m4 * 4);
                h2 h0 = __builtin_bit_cast(h2, hu.x);
                h2 h1 = __builtin_bit_cast(h2, hu.y);
                h2 h2v = __builtin_bit_cast(h2, hu.z);
                h2 h3 = __builtin_bit_cast(h2, hu.w);
                #pragma unroll
                for (int a = 0; a < 4; a++) {
                    acc[a][b] = __builtin_amdgcn_fdot2(w[a][m4 * 4],     h0,  acc[a][b], false);
                    acc[a][b] = __builtin_amdgcn_fdot2(w[a][m4 * 4 + 1], h1,  acc[a][b], false);
                    acc[a][b] = __builtin_amdgcn_fdot2(w[a][m4 * 4 + 2], h2v, acc[a][b], false);
                    acc[a][b] = __builtin_amdgcn_fdot2(w[a][m4 * 4 + 3], h3,  acc[a][b], false);
                }
                float4 cv = *(const float4*)(cb + m4 * 4);
                a3[b] += w3[m4].x * cv.x + w3[m4].y * cv.y + w3[m4].z * cv.z + w3[m4].w * cv.w;
            }
        }
        #pragma unroll
        for (int a = 0; a < 4; a++)
            #pragma unroll
            for (int b = 0; b < 8; b++) red[tid * 33 + a * 8 + b] = acc[a][b];
        #pragma unroll
        for (int b = 0; b < 8; b++) red2[tid * 9 + b] = a3[b];
        __syncthreads();

        // ---- elementwise (block-local) + two-phase per-wave publish ----
        {
            float g4[4];
            #pragma unroll
            for (int a = 0; a < 4; a++) {
                float s = 0.f;
                #pragma unroll
                for (int k = 0; k < 8; k++)
                    s += red[(k * 32 + tl) * 33 + a * 8 + bb];
                s += ppL[bb * 128 + a * 32 + tl] + hyv[a];
                if (upok) s += bUv[a];
                if (lfok) s += bLv[a];
                g4[a] = s;
            }
            float ci = 0.f;
            #pragma unroll
            for (int k = 0; k < 8; k++) ci += red2[(k * 32 + tl) * 9 + bb];
            if (cok) ci += b_cc[(c & 3) * 32 + tl];
            const float cnew = sigm(g4[1]) * ci + sigm(g4[0]) * tanh_fast(g4[2]);
            const float hnew = sigm(g4[3]) * tanh_fast(cnew);

            const int slot = (i & 3) * 32 + j;
            const size_t coIdx = (size_t)slot * 2048 + bb * 256 + c * 32 + tl;
            const size_t hoIdx = (size_t)slot * 1024 + bb * 128 + c * 16 + (tl >> 1);
            const float hOdd = __shfl_xor(hnew, 1);
            const unsigned hopk = __builtin_bit_cast(unsigned, pk_f16(hnew, hOdd));

            // phase 1: LEFT copies -> shared XCD L2 (fast drain + L2 flag)
            if (rowok && j < 31) {
                st_l2((unsigned*)&CoL[coIdx], __float_as_uint(cnew));
                if ((tl & 1) == 0) st_l2(&HoL[hoIdx], hopk);
                drain_vmem();
                if ((tid & 63) == 0)
                    st_l2(&WFL[((i * 8 + c) * 4 + (tid >> 6)) * 4], BASE + (unsigned)(j + 1));
            }
            // phase 2: UP copies (+ left fallback) via UC
            if (i < 31 || !rowok) {
                st_f32(&CoU[coIdx], cnew);
                if ((tl & 1) == 0) st_u32(&HoU[hoIdx], hopk);
            }
            if (i == 31 && j == 31)
                st_f32(&HoF[bb * 256 + c * 32 + tl], hnew);   // full-precision corner
        }
        // per-wave: drain own stores (wave-local vmcnt), then fire own UC flag.
        drain_vmem();
        if ((tid & 63) == 0)
            st_flag(&WFU[((i * 8 + c) * 4 + (tid >> 6)) * 4], BASE + (unsigned)(j + 1));
    }

    // ================= Final: condense ho(31,31) + MLP + softmax (bid 31) ==========
    if (bid == 31) {
        if (tid < 32)
            wait_ge(&WFU[((31 * 8 + (tid >> 2)) * 4 + (tid & 3)) * 4], 32u);
        __syncthreads();
        #pragma unroll
        for (int r = 0; r < 8; r++)
            sCo[r * 256 + tid] = ld_f32(&HoF[r * 256 + tid]);
        __syncthreads();
        // condense: hcond[b][o] = b_ch[o] + W_ch[o,:] @ ho[b,:]
        #pragma unroll 1
        for (int q = 0; q < 4; q++) {
            const int oo = tid + q * 256;
            const int b = oo >> 7, o = oo & 127;
            float a = b_ch[o];
            const float* wr = W_ch + (long)o * 256;
            const float* x = sCo + b * 256;
            for (int k = 0; k < 256; k += 4) {
                float4 wv = *(const float4*)(wr + k);
                float4 xv = *(const float4*)(x + k);
                a += wv.x * xv.x + wv.y * xv.y + wv.z * xv.z + wv.w * xv.w;
            }
            ppL[b * 128 + o] = a;
        }
        __syncthreads();
        float* m1 = red;          // [8][128]
        float* m2 = red + 1024;   // [8][128]
        for (int idx = tid; idx < 1024; idx += 256) {
            int b = idx >> 7, o = idx & 127;
            float a = b1[o];
            const float* wr = W1 + o * 128; const float* x = ppL + b * 128;
            for (int k = 0; k < 128; k++) a += wr[k] * x[k];
            m1[idx] = fmaxf(a, 0.f);
        }
        __syncthreads();
        for (int idx = tid; idx < 1024; idx += 256) {
            int b = idx >> 7, o = idx & 127;
            float a = b2[o];
            const float* wr = W2 + o * 128; const float* x = m1 + b * 128;
            for (int k = 0; k < 128; k++) a += wr[k] * x[k];
            m2[idx] = fmaxf(a, 0.f);
        }
        __syncthreads();
        if (tid < 8) {
            const int b = tid;
            float lg[3];
            for (int cc = 0; cc < 3; cc++) {
                float a = b3[cc];
                const float* wr = W3 + cc * 128; const float* x = m2 + b * 128;
                for (int k = 0; k < 128; k++) a += wr[k] * x[k];
                lg[cc] = a;
            }
            float m = fmaxf(lg[0], fmaxf(lg[1], lg[2]));
            float e0 = expf(lg[0] - m), e1 = expf(lg[1] - m), e2 = expf(lg[2] - m);
            float s = e0 + e1 + e2;
            out[b * 3 + 0] = e0 / s;
            out[b * 3 + 1] = e1 / s;
            out[b * 3 + 2] = e2 / s;
        }
    }
}

extern "C" void kernel_launch(void* const* d_in, const int* in_sizes, int n_in,
                              void* d_out, int out_size, void* d_ws, size_t ws_size,
                              hipStream_t stream) {
    const int*   premise    = (const int*)d_in[0];
    const int*   hypothesis = (const int*)d_in[1];
    const float* emb        = (const float*)d_in[2];
    const float* W_ih       = (const float*)d_in[3];
    const float* b_ih       = (const float*)d_in[4];
    const float* W_hh       = (const float*)d_in[5];
    const float* b_hh       = (const float*)d_in[6];
    const float* W_ch       = (const float*)d_in[7];
    const float* b_ch       = (const float*)d_in[8];
    const float* W_cc       = (const float*)d_in[9];
    const float* b_cc       = (const float*)d_in[10];
    const float* W1         = (const float*)d_in[11];
    const float* b1         = (const float*)d_in[12];
    const float* W2         = (const float*)d_in[13];
    const float* b2         = (const float*)d_in[14];
    const float* W3         = (const float*)d_in[15];
    const float* b3         = (const float*)d_in[16];
    float* out = (float*)d_out;
    float* ws  = (float*)d_ws;

    (void)in_sizes; (void)n_in; (void)out_size; (void)ws_size;

    grid_lstm_kernel<<<dim3(256), dim3(256), 0, stream>>>(
        premise, hypothesis, emb, W_ih, b_ih, W_hh, b_hh,
        W_ch, b_ch, W_cc, b_cc, W1, b1, W2, b2, W3, b3, out, ws);
}

// Round 5
// 115555.994 us; speedup vs baseline: 33.2170x; 33.2170x over previous
//
#include <hip/hip_runtime.h>
#include <math.h>

// GridLSTM one-flag-per-cell dataflow, fused f16 weights. V=50000,E=300,H=128,L=32,B=8.
// 256 blocks x 256 threads. bid = c*32 + i (i = grid row, c = t-slice chunk 0..7).
// gates = WU@ho_up + WL@ho_left + (Pproj+b) + Hypproj + upok*bU + lfok*bL
// with WU/WL precomputed f16x2 on device, consumed via v_dot2_f32_f16.
//
// R5: XCD-local LEFT exchange via shared per-XCD L2, with sc0 (L1-bypass) asm.
//   R4 post-mortem: `volatile` loads do NOT bypass L1 on gfx950 -> consumer
//   polls spun on a stale L1 line until the failsafe (3.8s, correct answer).
//   Producer sc0 stores DID reach L2 (answers were right). Fix: sc0 loads.
//   - L2 tier: global_load/store ... sc0 inline asm (single-inst helpers).
//   - Escape hatch: first left-wait (j==1) bounds its L2 spin at 2^16; on
//     timeout the block sets l2dead and falls back to the PROVEN R2 UC
//     protocol for the rest of the kernel. Producers dual-publish (L2 + UC
//     always) so the fallback is always data-complete.
//   - rowok: runtime check (s_getreg XCC_ID) that all 8 row-siblings share
//     an XCD; else UC fallback from the start (G16-safe).
//   Workspace layout identical to R4 (5.30 MB, harness-verified).

typedef _Float16 h2 __attribute__((ext_vector_type(2)));

__device__ __forceinline__ h2 pk_f16(float a, float b) {
    return __builtin_bit_cast(h2, __builtin_amdgcn_cvt_pkrtz(a, b));
}

// ---------------- workspace layout (float words) — total 1,325,056 (R4-proven) ----
#define HYP_OFF   0            // Hypproj [32 j][8 b][1024]            (atomic f32) 1MB
#define WP_OFF    262144       // fused wts packed h2 [1024 g][256]    (atomic u32) 1MB
#define B_OFF     524288       // bU[1024] | bL[1024]
#define INITF_OFF 526336       // InitF [p*4] (1024)
#define WFU_OFF   527360       // UC per-wave flags [((i*8+c)*4+w)*4] (4096)
#define WFL_OFF   531456       // L2 per-wave flags [((i*8+c)*4+w)*4] (4096)
#define XCD_OFF   535552       // per-block XCD id [bid*4] (1024)
#define HOU_OFF   536576       // Ho UC  u32 f16x2 [4][32][8][128] (512KB)
#define HOL_OFF   667648       // Ho L2  u32 f16x2 [4][32][8][128] (512KB)
#define COU_OFF   798720       // Co UC  f32 [4][32][8][256]       (1MB)
#define COL_OFF   1060864      // Co L2  f32 [4][32][8][256]       (1MB)
#define HOF_OFF   1323008      // final ho(31,31) f32 [8 b][256 t] (8KB)
// end = 1325056 floats = 5.30 MB

#define BASE 0xAAAAAAAAu

__device__ __forceinline__ float sigm(float x) { return 1.f / (1.f + __expf(-x)); }
__device__ __forceinline__ float tanh_fast(float x) { return 1.f - 2.f / (__expf(2.f * x) + 1.f); }

__device__ __forceinline__ unsigned ld_flag(const unsigned* p) {
    return __hip_atomic_load(p, __ATOMIC_RELAXED, __HIP_MEMORY_SCOPE_AGENT);
}
__device__ __forceinline__ void st_flag(unsigned* p, unsigned v) {
    __hip_atomic_store(p, v, __ATOMIC_RELAXED, __HIP_MEMORY_SCOPE_AGENT);
}
__device__ __forceinline__ float ld_f32(const float* p) {
    unsigned u = __hip_atomic_load((const unsigned*)p, __ATOMIC_RELAXED, __HIP_MEMORY_SCOPE_AGENT);
    return __uint_as_float(u);
}
__device__ __forceinline__ void st_f32(float* p, float v) {
    __hip_atomic_store((unsigned*)p, __float_as_uint(v), __ATOMIC_RELAXED, __HIP_MEMORY_SCOPE_AGENT);
}
__device__ __forceinline__ void st_u32(unsigned* p, unsigned v) {
    __hip_atomic_store(p, v, __ATOMIC_RELAXED, __HIP_MEMORY_SCOPE_AGENT);
}
__device__ __forceinline__ unsigned long long ld_u64(const unsigned long long* p) {
    return __hip_atomic_load(p, __ATOMIC_RELAXED, __HIP_MEMORY_SCOPE_AGENT);
}
__device__ __forceinline__ float2 ld_f32x2(const float* p) {   // 8B-aligned, UC
    unsigned long long u = ld_u64((const unsigned long long*)p);
    float2 r; r.x = __uint_as_float((unsigned)u); r.y = __uint_as_float((unsigned)(u >> 32));
    return r;
}
// ---- L2-tier primitives: sc0 = L1-bypass, hits the shared per-XCD L2 ----
__device__ __forceinline__ unsigned ld_sc0(const unsigned* p) {
    unsigned v;
    asm volatile("global_load_dword %0, %1, off sc0\n\t"
                 "s_waitcnt vmcnt(0)"
                 : "=&v"(v) : "v"(p) : "memory");
    return v;
}
__device__ __forceinline__ unsigned long long ld_sc0_u64(const void* p) {
    unsigned long long v;
    asm volatile("global_load_dwordx2 %0, %1, off sc0\n\t"
                 "s_waitcnt vmcnt(0)"
                 : "=&v"(v) : "v"(p) : "memory");
    return v;
}
__device__ __forceinline__ void st_sc0(unsigned* p, unsigned v) {
    asm volatile("global_store_dword %0, %1, off sc0" :: "v"(p), "v"(v) : "memory");
}
__device__ __forceinline__ void wait_ge(const unsigned* f, unsigned target) {
    long spins = 0;
    while ((ld_flag(f) - BASE) < target) {
        __builtin_amdgcn_s_sleep(1);
        if (++spins > (1L << 22)) break;   // failsafe: wrong answer > hang
    }
}
__device__ __forceinline__ void drain_vmem() {
    asm volatile("s_waitcnt vmcnt(0)" ::: "memory");
}
__device__ __forceinline__ unsigned xcc_id() {
    unsigned v;
    asm volatile("s_getreg_b32 %0, hwreg(HW_REG_XCC_ID)" : "=s"(v));
    return v & 0xFu;
}

__global__ void __launch_bounds__(256, 1) grid_lstm_kernel(
    const int* __restrict__ premise, const int* __restrict__ hypothesis,
    const float* __restrict__ emb,
    const float* __restrict__ W_ih, const float* __restrict__ b_ih,
    const float* __restrict__ W_hh, const float* __restrict__ b_hh,
    const float* __restrict__ W_ch, const float* __restrict__ b_ch,
    const float* __restrict__ W_cc, const float* __restrict__ b_cc,
    const float* __restrict__ W1, const float* __restrict__ b1,
    const float* __restrict__ W2, const float* __restrict__ b2,
    const float* __restrict__ W3, const float* __restrict__ b3,
    float* __restrict__ out, float* __restrict__ ws)
{
    __shared__ h2    hAB[2048];      // f16 [8 b][256 kk]: kk<128 up, kk>=128 left (8KB)
    __shared__ float sCo[2048];      // f32 co_side [8 b][256] (8KB)
    __shared__ float ppL[1024];      // Pproj slice [8 b][128 g], g=(a<<5)|s (4KB)
    __shared__ float red[8448];      // gate partials [256][33] / embs / MLP (33.8KB)
    __shared__ float red2[2304];     // c partials [256][9] (9.2KB)
    __shared__ int   l2dead_s;       // L2-tier health (decided at j==1)

    const int tid = threadIdx.x;
    const int bid = blockIdx.x;
    const int i   = bid & 31;       // grid row
    const int c   = bid >> 5;       // t-slice chunk

    float*    Hypproj = ws + HYP_OFF;
    unsigned* WP      = (unsigned*)(ws + WP_OFF);
    float*    BU      = ws + B_OFF;
    float*    BL      = ws + B_OFF + 1024;
    unsigned* InitF   = (unsigned*)(ws + INITF_OFF);
    unsigned* WFU     = (unsigned*)(ws + WFU_OFF);
    unsigned* WFL     = (unsigned*)(ws + WFL_OFF);
    unsigned* XCDA    = (unsigned*)(ws + XCD_OFF);
    unsigned* HoU     = (unsigned*)(ws + HOU_OFF);
    unsigned* HoL     = (unsigned*)(ws + HOL_OFF);
    float*    CoU     = ws + COU_OFF;
    float*    CoL     = ws + COL_OFF;
    float*    HoF     = ws + HOF_OFF;

    const int tq = tid & 31, ks = tid >> 5;   // GEMM K-split coords
    const int tl = tid & 31, bb = tid >> 5;   // elementwise coords (t_local, batch)
    const unsigned myxcd = xcc_id();

    // ================= Init A: Pproj (LDS) + Hypproj for this block's gate rows ====
    {
        float* embs = red;   // [2 sides][8][300] = 4800 floats
        for (int idx = tid; idx < 4800; idx += 256) {
            int side = idx / 2400, rem = idx - side * 2400;
            int b = rem / 300, e = rem - b * 300;
            const int* toks = side ? hypothesis : premise;
            embs[idx] = emb[(long)toks[b * 32 + i] * 300 + e];
        }
        __syncthreads();
        #pragma unroll 1
        for (int q = 0; q < 4; q++) {
            const int oo = tid + q * 256;
            const int b = oo >> 7, g = oo & 127;
            const int gr = (g >> 5) * 256 + c * 32 + (g & 31);   // t-sliced gate row
            float accP = b_ih[gr] + b_hh[gr];
            float accH = 0.f;
            const float* wp = W_ih + (long)gr * 600;
            const float* eP = embs + b * 300;
            const float* eH = embs + 2400 + b * 300;
            for (int e = 0; e < 300; e += 4) {
                float4 w1 = *(const float4*)(wp + e);
                float4 w2v = *(const float4*)(wp + 300 + e);
                float4 p4 = *(const float4*)(eP + e);
                float4 h4 = *(const float4*)(eH + e);
                accP += w1.x * p4.x + w1.y * p4.y + w1.z * p4.z + w1.w * p4.w;
                accH += w2v.x * h4.x + w2v.y * h4.y + w2v.z * h4.z + w2v.w * h4.w;
            }
            st_f32(&Hypproj[i * 8192 + b * 1024 + gr], accH);     // cross-block
            ppL[b * 128 + g] = accP;                              // block-local
        }
        __syncthreads();   // embs (red) free
    }

    // ================= Init B: fused weight rows [4*bid, 4*bid+4) =================
    {
        const int tr = tid >> 6, col = (tid & 63) * 4;
        const int r  = bid * 4 + tr;
        float u[4] = {0.f, 0.f, 0.f, 0.f}, l[4] = {0.f, 0.f, 0.f, 0.f};
        const float* whU = W_hh + (long)r * 256;
        const float* whL = whU + 128;
        for (int k = 0; k < 128; k++) {
            const float wu = whU[k], wl = whL[k];
            float4 wc = *(const float4*)(W_ch + (long)k * 256 + col);
            u[0] += wu * wc.x; u[1] += wu * wc.y; u[2] += wu * wc.z; u[3] += wu * wc.w;
            l[0] += wl * wc.x; l[1] += wl * wc.y; l[2] += wl * wc.z; l[3] += wl * wc.w;
        }
        unsigned* wrow = WP + (long)r * 256;
        st_u32(&wrow[col / 2],       __builtin_bit_cast(unsigned, __builtin_amdgcn_cvt_pkrtz(u[0], u[1])));
        st_u32(&wrow[col / 2 + 1],   __builtin_bit_cast(unsigned, __builtin_amdgcn_cvt_pkrtz(u[2], u[3])));
        st_u32(&wrow[128 + col / 2],     __builtin_bit_cast(unsigned, __builtin_amdgcn_cvt_pkrtz(l[0], l[1])));
        st_u32(&wrow[128 + col / 2 + 1], __builtin_bit_cast(unsigned, __builtin_amdgcn_cvt_pkrtz(l[2], l[3])));
        if ((tid & 63) == 0) {   // bias projections for this row
            float su = 0.f, sl = 0.f;
            for (int k = 0; k < 128; k++) { su += whU[k] * b_ch[k]; sl += whL[k] * b_ch[k]; }
            st_f32(&BU[r], su); st_f32(&BL[r], sl);
        }
        if (tid == 0) st_flag(&XCDA[bid * 4], BASE + 1u + myxcd);   // publish XCD id
    }
    drain_vmem();
    __syncthreads();
    if (tid == 0) st_flag(&InitF[bid * 4], BASE + 1u);

    // ---- wait ALL inits (covers every Hypproj row + weights + XCD ids) ----
    wait_ge(&InitF[tid * 4], 1u);
    // ---- row co-location check: all 8 siblings of row i on one XCD? ----
    int okv = 1;
    if (tid < 8) okv = (ld_flag(&XCDA[(tid * 32 + i) * 4]) == BASE + 1u + myxcd);
    const bool rowok = __syncthreads_and(okv) != 0;
    if (tid == 0) l2dead_s = 0;
    __syncthreads();

    // ---- load fused weight slice -> registers (f16x2), W_cc slice (fp32) ----
    h2 w[4][32];                  // 128 VGPRs
    #pragma unroll
    for (int a = 0; a < 4; a++) {
        const unsigned* src = WP + (long)(a * 256 + c * 32 + tq) * 256 + ks * 32;
        #pragma unroll
        for (int m = 0; m < 16; m++) {
            unsigned long long u2 = ld_u64((const unsigned long long*)(src + m * 2));
            w[a][2 * m]     = __builtin_bit_cast(h2, (unsigned)u2);
            w[a][2 * m + 1] = __builtin_bit_cast(h2, (unsigned)(u2 >> 32));
        }
    }
    float4 w3[8];                 // 32 VGPRs: W_cc row (c&3)*32+tq, K-seg ks*32..+32
    {
        const float* wr = W_cc + (long)((c & 3) * 32 + tq) * 256 + ks * 32;
        #pragma unroll
        for (int m = 0; m < 8; m++) w3[m] = *(const float4*)(wr + m * 4);
    }
    float bUv[4], bLv[4];
    #pragma unroll
    for (int a = 0; a < 4; a++) {
        bUv[a] = ld_f32(&BU[a * 256 + c * 32 + tl]);
        bLv[a] = ld_f32(&BL[a * 256 + c * 32 + tl]);
    }

    // ================= Wavefront: row i walks j = 0..31 =================
    #pragma unroll 1
    for (int j = 0; j < 32; j++) {
        const bool upok = (i > 0), lfok = (j > 0);
        const bool cok  = (c < 4) ? upok : lfok;
        const int  jl   = lfok ? (j - 1) : 0;

        // ---- prefetch Hypproj for elementwise (independent, overlaps the spin) ----
        float hyv[4];
        #pragma unroll
        for (int a = 0; a < 4; a++)
            hyv[a] = ld_f32(&Hypproj[j * 8192 + bb * 1024 + a * 256 + c * 32 + tl]);

        // ---- dependency wait: combined loop; up lanes UC, left lanes L2|UC ----
        const bool useL2 = rowok && (l2dead_s == 0);
        bool tmo = false;
        {
            bool pend = false, l2lane = false;
            const unsigned* fp = nullptr; unsigned tgt = 0;
            int fidxL = 0;
            if (upok && tid < 32) {
                fp = &WFU[(((i - 1) * 8 + (tid >> 2)) * 4 + (tid & 3)) * 4];
                tgt = (unsigned)(j + 1); pend = true;
            } else if (lfok && tid >= 32 && tid < 60) {
                int s = tid - 32;
                int cc = s >> 2;
                cc += (cc >= c) ? 1 : 0;          // skip self (own stores drained already)
                fidxL = ((i * 8 + cc) * 4 + (s & 3)) * 4;
                fp = useL2 ? &WFL[fidxL] : &WFU[fidxL];
                l2lane = useL2;
                tgt = (unsigned)j; pend = true;
            }
            long spins = 0;
            while (__any((int)pend)) {
                if (pend) {
                    unsigned v = l2lane ? ld_sc0(fp) : ld_flag(fp);
                    if (v - BASE >= tgt) pend = false;
                }
                if (__any((int)pend)) {
                    __builtin_amdgcn_s_sleep(1);
                    ++spins;
                    if (l2lane && pend && spins > (1L << 16)) { tmo = true; pend = false; }
                    if (spins > (1L << 22)) break;   // global failsafe
                }
            }
            if (__syncthreads_or((int)tmo)) {
                // L2 tier unhealthy: permanent UC fallback (proven R2 protocol).
                if (tid == 0) l2dead_s = 1;
                if (lfok && tid >= 32 && tid < 60)
                    wait_ge(&WFU[fidxL], (unsigned)j);
                tmo = true;   // broadcast: don't trust L2 data this step
            }
        }
        __syncthreads();
        const bool dataL2 = useL2 && !tmo;

        // ---- one bulk load + LDS stage (flags imply visibility; no retries) ----
        const unsigned* HoUp  = HoU + (size_t)(((i - 1) & 3) * 32 + j) * 1024;
        const size_t    lslot = (size_t)((i & 3) * 32 + jl);
        const unsigned* HoLfL = HoL + lslot * 1024;   // L2 tier
        const unsigned* HoLfU = HoU + lslot * 1024;   // UC fallback
        const float*    CoUp  = CoU + (size_t)(((i - 1) & 3) * 32 + j) * 2048;
        const float*    CoLfL = CoL + lslot * 2048;
        const float*    CoLfU = CoU + lslot * 2048;
        #pragma unroll
        for (int r = 0; r < 4; r++) {
            const int idx = r * 256 + tid;           // 0..1023
            const int b = idx >> 7, kk = idx & 127;  // f16 pair (2kk, 2kk+1)
            unsigned u = upok ? ld_flag(HoUp + b * 128 + kk) : 0u;
            unsigned l = 0u;
            if (lfok)
                l = dataL2 ? ld_sc0(HoLfL + b * 128 + kk)
                           : ld_flag(HoLfU + b * 128 + kk);
            float2 cv = make_float2(0.f, 0.f);
            if (cok) {
                if (c < 4) {
                    cv = ld_f32x2(CoUp + b * 256 + 2 * kk);        // up, UC
                } else if (dataL2) {
                    unsigned long long q = ld_sc0_u64(CoLfL + b * 256 + 2 * kk);
                    cv.x = __uint_as_float((unsigned)q);
                    cv.y = __uint_as_float((unsigned)(q >> 32));
                } else {
                    cv = ld_f32x2(CoLfU + b * 256 + 2 * kk);       // left, UC
                }
            }
            hAB[b * 256 + kk]       = __builtin_bit_cast(h2, u);   // 0u == f16 pair (0,0)
            hAB[b * 256 + 128 + kk] = __builtin_bit_cast(h2, l);
            sCo[b * 256 + 2 * kk] = cv.x; sCo[b * 256 + 2 * kk + 1] = cv.y;
        }
        __syncthreads();

        // ---- fused gates GEMM (f16 dot2) + c-path (fp32) ----
        float acc[4][8], a3[8];
        #pragma unroll
        for (int a = 0; a < 4; a++)
            #pragma unroll
            for (int b = 0; b < 8; b++) acc[a][b] = 0.f;
        #pragma unroll
        for (int b = 0; b < 8; b++) a3[b] = 0.f;
        #pragma unroll
        for (int b = 0; b < 8; b++) {
            const h2*    hb = hAB + b * 256 + ks * 32;
            const float* cb = sCo + b * 256 + ks * 32;
            #pragma unroll
            for (int m4 = 0; m4 < 8; m4++) {
                uint4 hu = *(const uint4*)(hb + m4 * 4);
                h2 h0 = __builtin_bit_cast(h2, hu.x);
                h2 h1 = __builtin_bit_cast(h2, hu.y);
                h2 h2v = __builtin_bit_cast(h2, hu.z);
                h2 h3 = __builtin_bit_cast(h2, hu.w);
                #pragma unroll
                for (int a = 0; a < 4; a++) {
                    acc[a][b] = __builtin_amdgcn_fdot2(w[a][m4 * 4],     h0,  acc[a][b], false);
                    acc[a][b] = __builtin_amdgcn_fdot2(w[a][m4 * 4 + 1], h1,  acc[a][b], false);
                    acc[a][b] = __builtin_amdgcn_fdot2(w[a][m4 * 4 + 2], h2v, acc[a][b], false);
                    acc[a][b] = __builtin_amdgcn_fdot2(w[a][m4 * 4 + 3], h3,  acc[a][b], false);
                }
                float4 cv = *(const float4*)(cb + m4 * 4);
                a3[b] += w3[m4].x * cv.x + w3[m4].y * cv.y + w3[m4].z * cv.z + w3[m4].w * cv.w;
            }
        }
        #pragma unroll
        for (int a = 0; a < 4; a++)
            #pragma unroll
            for (int b = 0; b < 8; b++) red[tid * 33 + a * 8 + b] = acc[a][b];
        #pragma unroll
        for (int b = 0; b < 8; b++) red2[tid * 9 + b] = a3[b];
        __syncthreads();

        // ---- elementwise (block-local) + two-phase per-wave publish ----
        {
            float g4[4];
            #pragma unroll
            for (int a = 0; a < 4; a++) {
                float s = 0.f;
                #pragma unroll
                for (int k = 0; k < 8; k++)
                    s += red[(k * 32 + tl) * 33 + a * 8 + bb];
                s += ppL[bb * 128 + a * 32 + tl] + hyv[a];
                if (upok) s += bUv[a];
                if (lfok) s += bLv[a];
                g4[a] = s;
            }
            float ci = 0.f;
            #pragma unroll
            for (int k = 0; k < 8; k++) ci += red2[(k * 32 + tl) * 9 + bb];
            if (cok) ci += b_cc[(c & 3) * 32 + tl];
            const float cnew = sigm(g4[1]) * ci + sigm(g4[0]) * tanh_fast(g4[2]);
            const float hnew = sigm(g4[3]) * tanh_fast(cnew);

            const int slot = (i & 3) * 32 + j;
            const size_t coIdx = (size_t)slot * 2048 + bb * 256 + c * 32 + tl;
            const size_t hoIdx = (size_t)slot * 1024 + bb * 128 + c * 16 + (tl >> 1);
            const float hOdd = __shfl_xor(hnew, 1);
            const unsigned hopk = __builtin_bit_cast(unsigned, pk_f16(hnew, hOdd));

            // phase 1: LEFT copies -> shared XCD L2 (fast drain + L2 flag)
            if (rowok && j < 31) {
                st_sc0((unsigned*)&CoL[coIdx], __float_as_uint(cnew));
                if ((tl & 1) == 0) st_sc0(&HoL[hoIdx], hopk);
                drain_vmem();
                if ((tid & 63) == 0)
                    st_sc0(&WFL[((i * 8 + c) * 4 + (tid >> 6)) * 4], BASE + (unsigned)(j + 1));
            }
            // phase 2: UC copies ALWAYS (up consumers + left fallback + final)
            st_f32(&CoU[coIdx], cnew);
            if ((tl & 1) == 0) st_u32(&HoU[hoIdx], hopk);
            if (i == 31 && j == 31)
                st_f32(&HoF[bb * 256 + c * 32 + tl], hnew);   // full-precision corner
        }
        // per-wave: drain own stores (wave-local vmcnt), then fire own UC flag.
        drain_vmem();
        if ((tid & 63) == 0)
            st_flag(&WFU[((i * 8 + c) * 4 + (tid >> 6)) * 4], BASE + (unsigned)(j + 1));
    }

    // ================= Final: condense ho(31,31) + MLP + softmax (bid 31) ==========
    if (bid == 31) {
        if (tid < 32)
            wait_ge(&WFU[((31 * 8 + (tid >> 2)) * 4 + (tid & 3)) * 4], 32u);
        __syncthreads();
        #pragma unroll
        for (int r = 0; r < 8; r++)
            sCo[r * 256 + tid] = ld_f32(&HoF[r * 256 + tid]);
        __syncthreads();
        // condense: hcond[b][o] = b_ch[o] + W_ch[o,:] @ ho[b,:]
        #pragma unroll 1
        for (int q = 0; q < 4; q++) {
            const int oo = tid + q * 256;
            const int b = oo >> 7, o = oo & 127;
            float a = b_ch[o];
            const float* wr = W_ch + (long)o * 256;
            const float* x = sCo + b * 256;
            for (int k = 0; k < 256; k += 4) {
                float4 wv = *(const float4*)(wr + k);
                float4 xv = *(const float4*)(x + k);
                a += wv.x * xv.x + wv.y * xv.y + wv.z * xv.z + wv.w * xv.w;
            }
            ppL[b * 128 + o] = a;
        }
        __syncthreads();
        float* m1 = red;          // [8][128]
        float* m2 = red + 1024;   // [8][128]
        for (int idx = tid; idx < 1024; idx += 256) {
            int b = idx >> 7, o = idx & 127;
            float a = b1[o];
            const float* wr = W1 + o * 128; const float* x = ppL + b * 128;
            for (int k = 0; k < 128; k++) a += wr[k] * x[k];
            m1[idx] = fmaxf(a, 0.f);
        }
        __syncthreads();
        for (int idx = tid; idx < 1024; idx += 256) {
            int b = idx >> 7, o = idx & 127;
            float a = b2[o];
            const float* wr = W2 + o * 128; const float* x = m1 + b * 128;
            for (int k = 0; k < 128; k++) a += wr[k] * x[k];
            m2[idx] = fmaxf(a, 0.f);
        }
        __syncthreads();
        if (tid < 8) {
            const int b = tid;
            float lg[3];
            for (int cc = 0; cc < 3; cc++) {
                float a = b3[cc];
                const float* wr = W3 + cc * 128; const float* x = m2 + b * 128;
                for (int k = 0; k < 128; k++) a += wr[k] * x[k];
                lg[cc] = a;
            }
            float m = fmaxf(lg[0], fmaxf(lg[1], lg[2]));
            float e0 = expf(lg[0] - m), e1 = expf(lg[1] - m), e2 = expf(lg[2] - m);
            float s = e0 + e1 + e2;
            out[b * 3 + 0] = e0 / s;
            out[b * 3 + 1] = e1 / s;
            out[b * 3 + 2] = e2 / s;
        }
    }
}

extern "C" void kernel_launch(void* const* d_in, const int* in_sizes, int n_in,
                              void* d_out, int out_size, void* d_ws, size_t ws_size,
                              hipStream_t stream) {
    const int*   premise    = (const int*)d_in[0];
    const int*   hypothesis = (const int*)d_in[1];
    const float* emb        = (const float*)d_in[2];
    const float* W_ih       = (const float*)d_in[3];
    const float* b_ih       = (const float*)d_in[4];
    const float* W_hh       = (const float*)d_in[5];
    const float* b_hh       = (const float*)d_in[6];
    const float* W_ch       = (const float*)d_in[7];
    const float* b_ch       = (const float*)d_in[8];
    const float* W_cc       = (const float*)d_in[9];
    const float* b_cc       = (const float*)d_in[10];
    const float* W1         = (const float*)d_in[11];
    const float* b1         = (const float*)d_in[12];
    const float* W2         = (const float*)d_in[13];
    const float* b2         = (const float*)d_in[14];
    const float* W3         = (const float*)d_in[15];
    const float* b3         = (const float*)d_in[16];
    float* out = (float*)d_out;
    float* ws  = (float*)d_ws;

    (void)in_sizes; (void)n_in; (void)out_size; (void)ws_size;

    grid_lstm_kernel<<<dim3(256), dim3(256), 0, stream>>>(
        premise, hypothesis, emb, W_ih, b_ih, W_hh, b_hh,
        W_ch, b_ch, W_cc, b_cc, W1, b1, W2, b2, W3, b3, out, ws);
}

// Round 6
// 764.633 us; speedup vs baseline: 5019.9572x; 151.1262x over previous
//
#include <hip/hip_runtime.h>
#include <math.h>

// GridLSTM one-flag-per-cell dataflow, fused f16 weights. V=50000,E=300,H=128,L=32,B=8.
// 256 blocks x 256 threads. bid = c*32 + i (i = grid row, c = t-slice chunk 0..7).
// gates = WU@ho_up + WL@ho_left + (Pproj+b) + Hypproj + upok*bU + lfok*bL
// with WU/WL precomputed f16x2 on device, consumed via v_dot2_f32_f16.
//
// R6 = R2 (720us proven) + BATCHED staging loads.
//   R2's staging r-loop interleaved global loads with the dependent LDS writes:
//   the compiler emits load -> waitcnt -> ds_write x4, serializing ~4 L3 round
//   trips (~3.6us) on the critical path of EVERY hop. R6 issues ALL 16 global
//   loads (up-Ho x4, left-Ho x4, Co x4, Hypproj x4) into registers first,
//   fences instruction motion with sched_barrier(0), then does the LDS writes:
//   one overlapped RT instead of four serial ones.
//   Protocol unchanged from R2: per-wave UC flags; producer per-wave drain
//   (wave-local vmcnt) + own flag, no producer barrier; consumer 60-lane
//   combined spin. L2/sc0 transport abandoned (R4/R5 falsified it).

typedef _Float16 h2 __attribute__((ext_vector_type(2)));

__device__ __forceinline__ h2 pk_f16(float a, float b) {
    return __builtin_bit_cast(h2, __builtin_amdgcn_cvt_pkrtz(a, b));
}

// ---------------- workspace layout (float words) ----------------
#define HYP_OFF   0            // Hypproj [32 j][8 b][1024]            (atomic f32)
#define WP_OFF    262144       // fused wts packed h2 [1024 g][256]    (atomic u32)
#define B_OFF     524288       // bU[1024] | bL[1024]
#define INITF_OFF 526336       // InitF [p*16] (4096)
#define WF_OFF    530432       // per-wave flags [(i*8+c)*4 + w]*16 (16384)
#define HO_OFF    546816       // Ho f16x2 u32 [4 dep][32 j][8 b][128 kk] (512KB)
#define CO_OFF    677888       // Co f32 [4 dep][32 j][8 b][256 t]        (1MB)
#define HOF_OFF   940032       // final ho(31,31) f32 [8 b][256 t]        (8KB)
// end = 942080 floats = 3.77 MB of ws

#define BASE 0xAAAAAAAAu

__device__ __forceinline__ float sigm(float x) { return 1.f / (1.f + __expf(-x)); }
__device__ __forceinline__ float tanh_fast(float x) { return 1.f - 2.f / (__expf(2.f * x) + 1.f); }

__device__ __forceinline__ unsigned ld_flag(const unsigned* p) {
    return __hip_atomic_load(p, __ATOMIC_RELAXED, __HIP_MEMORY_SCOPE_AGENT);
}
__device__ __forceinline__ void st_flag(unsigned* p, unsigned v) {
    __hip_atomic_store(p, v, __ATOMIC_RELAXED, __HIP_MEMORY_SCOPE_AGENT);
}
__device__ __forceinline__ float ld_f32(const float* p) {
    unsigned u = __hip_atomic_load((const unsigned*)p, __ATOMIC_RELAXED, __HIP_MEMORY_SCOPE_AGENT);
    return __uint_as_float(u);
}
__device__ __forceinline__ void st_f32(float* p, float v) {
    __hip_atomic_store((unsigned*)p, __float_as_uint(v), __ATOMIC_RELAXED, __HIP_MEMORY_SCOPE_AGENT);
}
__device__ __forceinline__ void st_u32(unsigned* p, unsigned v) {
    __hip_atomic_store(p, v, __ATOMIC_RELAXED, __HIP_MEMORY_SCOPE_AGENT);
}
__device__ __forceinline__ unsigned long long ld_u64(const unsigned long long* p) {
    return __hip_atomic_load(p, __ATOMIC_RELAXED, __HIP_MEMORY_SCOPE_AGENT);
}
__device__ __forceinline__ float2 ld_f32x2(const float* p) {   // 8B-aligned
    unsigned long long u = ld_u64((const unsigned long long*)p);
    float2 r; r.x = __uint_as_float((unsigned)u); r.y = __uint_as_float((unsigned)(u >> 32));
    return r;
}
__device__ __forceinline__ void wait_ge(const unsigned* f, unsigned target) {
    long spins = 0;
    while ((ld_flag(f) - BASE) < target) {
        __builtin_amdgcn_s_sleep(1);
        if (++spins > (1L << 22)) break;   // failsafe: wrong answer > hang
    }
}
__device__ __forceinline__ void drain_vmem() {
    asm volatile("s_waitcnt vmcnt(0)" ::: "memory");
}

__global__ void __launch_bounds__(256, 1) grid_lstm_kernel(
    const int* __restrict__ premise, const int* __restrict__ hypothesis,
    const float* __restrict__ emb,
    const float* __restrict__ W_ih, const float* __restrict__ b_ih,
    const float* __restrict__ W_hh, const float* __restrict__ b_hh,
    const float* __restrict__ W_ch, const float* __restrict__ b_ch,
    const float* __restrict__ W_cc, const float* __restrict__ b_cc,
    const float* __restrict__ W1, const float* __restrict__ b1,
    const float* __restrict__ W2, const float* __restrict__ b2,
    const float* __restrict__ W3, const float* __restrict__ b3,
    float* __restrict__ out, float* __restrict__ ws)
{
    __shared__ h2    hAB[2048];      // f16 [8 b][256 kk]: kk<128 up, kk>=128 left (8KB)
    __shared__ float sCo[2048];      // f32 co_side [8 b][256] (8KB)
    __shared__ float ppL[1024];      // Pproj slice [8 b][128 g], g=(a<<5)|s (4KB)
    __shared__ float red[8448];      // gate partials [256][33] / embs / MLP (33.8KB)
    __shared__ float red2[2304];     // c partials [256][9] (9.2KB)

    const int tid = threadIdx.x;
    const int bid = blockIdx.x;
    const int i   = bid & 31;       // grid row
    const int c   = bid >> 5;       // t-slice chunk

    float*    Hypproj = ws + HYP_OFF;
    unsigned* WP      = (unsigned*)(ws + WP_OFF);
    float*    BU      = ws + B_OFF;
    float*    BL      = ws + B_OFF + 1024;
    unsigned* InitF   = (unsigned*)(ws + INITF_OFF);   // [p*16]
    unsigned* WF      = (unsigned*)(ws + WF_OFF);      // [((i*8+c)*4+w)*16]
    unsigned* Ho      = (unsigned*)(ws + HO_OFF);      // f16x2 per entry
    float*    Co      = ws + CO_OFF;
    float*    HoF     = ws + HOF_OFF;

    const int tq = tid & 31, ks = tid >> 5;   // GEMM K-split coords
    const int tl = tid & 31, bb = tid >> 5;   // elementwise coords (t_local, batch)

    // ================= Init A: Pproj (LDS) + Hypproj for this block's gate rows ====
    {
        float* embs = red;   // [2 sides][8][300] = 4800 floats
        for (int idx = tid; idx < 4800; idx += 256) {
            int side = idx / 2400, rem = idx - side * 2400;
            int b = rem / 300, e = rem - b * 300;
            const int* toks = side ? hypothesis : premise;
            embs[idx] = emb[(long)toks[b * 32 + i] * 300 + e];
        }
        __syncthreads();
        #pragma unroll 1
        for (int q = 0; q < 4; q++) {
            const int oo = tid + q * 256;
            const int b = oo >> 7, g = oo & 127;
            const int gr = (g >> 5) * 256 + c * 32 + (g & 31);   // t-sliced gate row
            float accP = b_ih[gr] + b_hh[gr];
            float accH = 0.f;
            const float* wp = W_ih + (long)gr * 600;
            const float* eP = embs + b * 300;
            const float* eH = embs + 2400 + b * 300;
            for (int e = 0; e < 300; e += 4) {
                float4 w1 = *(const float4*)(wp + e);
                float4 w2v = *(const float4*)(wp + 300 + e);
                float4 p4 = *(const float4*)(eP + e);
                float4 h4 = *(const float4*)(eH + e);
                accP += w1.x * p4.x + w1.y * p4.y + w1.z * p4.z + w1.w * p4.w;
                accH += w2v.x * h4.x + w2v.y * h4.y + w2v.z * h4.z + w2v.w * h4.w;
            }
            st_f32(&Hypproj[i * 8192 + b * 1024 + gr], accH);     // cross-block
            ppL[b * 128 + g] = accP;                              // block-local
        }
        __syncthreads();   // embs (red) free
    }

    // ================= Init B: fused weight rows [4*bid, 4*bid+4) =================
    {
        const int tr = tid >> 6, col = (tid & 63) * 4;
        const int r  = bid * 4 + tr;
        float u[4] = {0.f, 0.f, 0.f, 0.f}, l[4] = {0.f, 0.f, 0.f, 0.f};
        const float* whU = W_hh + (long)r * 256;
        const float* whL = whU + 128;
        for (int k = 0; k < 128; k++) {
            const float wu = whU[k], wl = whL[k];
            float4 wc = *(const float4*)(W_ch + (long)k * 256 + col);
            u[0] += wu * wc.x; u[1] += wu * wc.y; u[2] += wu * wc.z; u[3] += wu * wc.w;
            l[0] += wl * wc.x; l[1] += wl * wc.y; l[2] += wl * wc.z; l[3] += wl * wc.w;
        }
        unsigned* wrow = WP + (long)r * 256;
        st_u32(&wrow[col / 2],       __builtin_bit_cast(unsigned, __builtin_amdgcn_cvt_pkrtz(u[0], u[1])));
        st_u32(&wrow[col / 2 + 1],   __builtin_bit_cast(unsigned, __builtin_amdgcn_cvt_pkrtz(u[2], u[3])));
        st_u32(&wrow[128 + col / 2],     __builtin_bit_cast(unsigned, __builtin_amdgcn_cvt_pkrtz(l[0], l[1])));
        st_u32(&wrow[128 + col / 2 + 1], __builtin_bit_cast(unsigned, __builtin_amdgcn_cvt_pkrtz(l[2], l[3])));
        if ((tid & 63) == 0) {   // bias projections for this row
            float su = 0.f, sl = 0.f;
            for (int k = 0; k < 128; k++) { su += whU[k] * b_ch[k]; sl += whL[k] * b_ch[k]; }
            st_f32(&BU[r], su); st_f32(&BL[r], sl);
        }
    }
    drain_vmem();
    __syncthreads();
    if (tid == 0) st_flag(&InitF[bid * 16], BASE + 1u);

    // ---- wait ALL inits (covers every Hypproj row + all fused weights) ----
    wait_ge(&InitF[tid * 16], 1u);
    __syncthreads();

    // ---- load fused weight slice -> registers (f16x2), W_cc slice (fp32) ----
    h2 w[4][32];                  // 128 VGPRs
    #pragma unroll
    for (int a = 0; a < 4; a++) {
        const unsigned* src = WP + (long)(a * 256 + c * 32 + tq) * 256 + ks * 32;
        #pragma unroll
        for (int m = 0; m < 16; m++) {
            unsigned long long u2 = ld_u64((const unsigned long long*)(src + m * 2));
            w[a][2 * m]     = __builtin_bit_cast(h2, (unsigned)u2);
            w[a][2 * m + 1] = __builtin_bit_cast(h2, (unsigned)(u2 >> 32));
        }
    }
    float4 w3[8];                 // 32 VGPRs: W_cc row (c&3)*32+tq, K-seg ks*32..+32
    {
        const float* wr = W_cc + (long)((c & 3) * 32 + tq) * 256 + ks * 32;
        #pragma unroll
        for (int m = 0; m < 8; m++) w3[m] = *(const float4*)(wr + m * 4);
    }
    float bUv[4], bLv[4];
    #pragma unroll
    for (int a = 0; a < 4; a++) {
        bUv[a] = ld_f32(&BU[a * 256 + c * 32 + tl]);
        bLv[a] = ld_f32(&BL[a * 256 + c * 32 + tl]);
    }

    // ================= Wavefront: row i walks j = 0..31 =================
    #pragma unroll 1
    for (int j = 0; j < 32; j++) {
        const bool upok = (i > 0), lfok = (j > 0);
        const bool cok  = (c < 4) ? upok : lfok;
        const int  jl   = lfok ? (j - 1) : 0;

        // ---- fine-grained dependency wait: 60 lanes, one per-wave flag each ----
        // lanes 0..31 : up blocks (i-1, cc=tid>>2), wave tid&3, target j+1
        // lanes 32..59: left siblings (i, cc != c), wave (tid-32)&3, target j
        {
            const unsigned* fp = nullptr;
            unsigned tgt = 0;
            if (upok && tid < 32) {
                fp = &WF[(((i - 1) * 8 + (tid >> 2)) * 4 + (tid & 3)) * 16];
                tgt = (unsigned)(j + 1);
            } else if (lfok && tid >= 32 && tid < 60) {
                int s = tid - 32;
                int cc = s >> 2;
                cc += (cc >= c) ? 1 : 0;          // skip self (own waves drained already)
                fp = &WF[((i * 8 + cc) * 4 + (s & 3)) * 16];
                tgt = (unsigned)j;
            }
            if (fp) wait_ge(fp, tgt);             // lanes exit individually; up & left concurrent
        }
        __syncthreads();

        // ---- BATCHED staging: issue ALL 16 global loads, then all LDS writes ----
        const unsigned* HoUp = Ho + (size_t)(((i - 1) & 3) * 32 + j) * 1024;
        const unsigned* HoLf = Ho + (size_t)((i & 3) * 32 + jl) * 1024;
        const float*    CoS  = (c < 4)
            ? Co + (size_t)(((i - 1) & 3) * 32 + j) * 2048
            : Co + (size_t)((i & 3) * 32 + jl) * 2048;
        const int hi = tid >> 7, kk = tid & 127;   // b = 2r + hi, kk fixed across r

        float hyv[4];
        #pragma unroll
        for (int a = 0; a < 4; a++)
            hyv[a] = ld_f32(&Hypproj[j * 8192 + bb * 1024 + a * 256 + c * 32 + tl]);
        unsigned uu[4], ll[4];
        float2   cc2[4];
        #pragma unroll
        for (int r = 0; r < 4; r++)
            uu[r] = upok ? ld_flag(HoUp + (2 * r + hi) * 128 + kk) : 0u;
        #pragma unroll
        for (int r = 0; r < 4; r++)
            ll[r] = lfok ? ld_flag(HoLf + (2 * r + hi) * 128 + kk) : 0u;
        #pragma unroll
        for (int r = 0; r < 4; r++)
            cc2[r] = cok ? ld_f32x2(CoS + (2 * r + hi) * 256 + 2 * kk) : make_float2(0.f, 0.f);
        __builtin_amdgcn_sched_barrier(0);   // keep all loads issued before LDS writes
        #pragma unroll
        for (int r = 0; r < 4; r++) {
            const int b = 2 * r + hi;
            hAB[b * 256 + kk]       = __builtin_bit_cast(h2, uu[r]);   // 0u == f16 pair (0,0)
            hAB[b * 256 + 128 + kk] = __builtin_bit_cast(h2, ll[r]);
            sCo[b * 256 + 2 * kk]     = cc2[r].x;
            sCo[b * 256 + 2 * kk + 1] = cc2[r].y;
        }
        __syncthreads();

        // ---- fused gates GEMM (f16 dot2) + c-path (fp32) ----
        float acc[4][8], a3[8];
        #pragma unroll
        for (int a = 0; a < 4; a++)
            #pragma unroll
            for (int b = 0; b < 8; b++) acc[a][b] = 0.f;
        #pragma unroll
        for (int b = 0; b < 8; b++) a3[b] = 0.f;
        #pragma unroll
        for (int b = 0; b < 8; b++) {
            const h2*    hb = hAB + b * 256 + ks * 32;
            const float* cb = sCo + b * 256 + ks * 32;
            #pragma unroll
            for (int m4 = 0; m4 < 8; m4++) {
                uint4 hu = *(const uint4*)(hb + m4 * 4);
                h2 h0 = __builtin_bit_cast(h2, hu.x);
                h2 h1 = __builtin_bit_cast(h2, hu.y);
                h2 h2v = __builtin_bit_cast(h2, hu.z);
                h2 h3 = __builtin_bit_cast(h2, hu.w);
                #pragma unroll
                for (int a = 0; a < 4; a++) {
                    acc[a][b] = __builtin_amdgcn_fdot2(w[a][m4 * 4],     h0,  acc[a][b], false);
                    acc[a][b] = __builtin_amdgcn_fdot2(w[a][m4 * 4 + 1], h1,  acc[a][b], false);
                    acc[a][b] = __builtin_amdgcn_fdot2(w[a][m4 * 4 + 2], h2v, acc[a][b], false);
                    acc[a][b] = __builtin_amdgcn_fdot2(w[a][m4 * 4 + 3], h3,  acc[a][b], false);
                }
                float4 cv = *(const float4*)(cb + m4 * 4);
                a3[b] += w3[m4].x * cv.x + w3[m4].y * cv.y + w3[m4].z * cv.z + w3[m4].w * cv.w;
            }
        }
        #pragma unroll
        for (int a = 0; a < 4; a++)
            #pragma unroll
            for (int b = 0; b < 8; b++) red[tid * 33 + a * 8 + b] = acc[a][b];
        #pragma unroll
        for (int b = 0; b < 8; b++) red2[tid * 9 + b] = a3[b];
        __syncthreads();

        // ---- elementwise (block-local) + per-wave publish + per-wave flag ----
        {
            float g4[4];
            #pragma unroll
            for (int a = 0; a < 4; a++) {
                float s = 0.f;
                #pragma unroll
                for (int k = 0; k < 8; k++)
                    s += red[(k * 32 + tl) * 33 + a * 8 + bb];
                s += ppL[bb * 128 + a * 32 + tl] + hyv[a];
                if (upok) s += bUv[a];
                if (lfok) s += bLv[a];
                g4[a] = s;
            }
            float ci = 0.f;
            #pragma unroll
            for (int k = 0; k < 8; k++) ci += red2[(k * 32 + tl) * 9 + bb];
            if (cok) ci += b_cc[(c & 3) * 32 + tl];
            const float cnew = sigm(g4[1]) * ci + sigm(g4[0]) * tanh_fast(g4[2]);
            const float hnew = sigm(g4[3]) * tanh_fast(cnew);

            const int slot = (i & 3) * 32 + j;
            st_f32(&Co[(size_t)slot * 2048 + bb * 256 + c * 32 + tl], cnew);
            const float hOdd = __shfl_xor(hnew, 1);
            if ((tl & 1) == 0)
                st_u32(&Ho[(size_t)slot * 1024 + bb * 128 + c * 16 + (tl >> 1)],
                       __builtin_bit_cast(unsigned, pk_f16(hnew, hOdd)));
            if (i == 31 && j == 31)
                st_f32(&HoF[bb * 256 + c * 32 + tl], hnew);   // full-precision corner
        }
        // per-wave: drain own stores (wave-local vmcnt), then fire own flag.
        // No cross-wave barrier: consumers wait each wave's flag separately.
        drain_vmem();
        if ((tid & 63) == 0)
            st_flag(&WF[((i * 8 + c) * 4 + (tid >> 6)) * 16], BASE + (unsigned)(j + 1));
    }

    // ================= Final: condense ho(31,31) + MLP + softmax (bid 31) ==========
    if (bid == 31) {
        if (tid < 32)
            wait_ge(&WF[((31 * 8 + (tid >> 2)) * 4 + (tid & 3)) * 16], 32u);
        __syncthreads();
        #pragma unroll
        for (int r = 0; r < 8; r++)
            sCo[r * 256 + tid] = ld_f32(&HoF[r * 256 + tid]);
        __syncthreads();
        // condense: hcond[b][o] = b_ch[o] + W_ch[o,:] @ ho[b,:]
        #pragma unroll 1
        for (int q = 0; q < 4; q++) {
            const int oo = tid + q * 256;
            const int b = oo >> 7, o = oo & 127;
            float a = b_ch[o];
            const float* wr = W_ch + (long)o * 256;
            const float* x = sCo + b * 256;
            for (int k = 0; k < 256; k += 4) {
                float4 wv = *(const float4*)(wr + k);
                float4 xv = *(const float4*)(x + k);
                a += wv.x * xv.x + wv.y * xv.y + wv.z * xv.z + wv.w * xv.w;
            }
            ppL[b * 128 + o] = a;
        }
        __syncthreads();
        float* m1 = red;          // [8][128]
        float* m2 = red + 1024;   // [8][128]
        for (int idx = tid; idx < 1024; idx += 256) {
            int b = idx >> 7, o = idx & 127;
            float a = b1[o];
            const float* wr = W1 + o * 128; const float* x = ppL + b * 128;
            for (int k = 0; k < 128; k++) a += wr[k] * x[k];
            m1[idx] = fmaxf(a, 0.f);
        }
        __syncthreads();
        for (int idx = tid; idx < 1024; idx += 256) {
            int b = idx >> 7, o = idx & 127;
            float a = b2[o];
            const float* wr = W2 + o * 128; const float* x = m1 + b * 128;
            for (int k = 0; k < 128; k++) a += wr[k] * x[k];
            m2[idx] = fmaxf(a, 0.f);
        }
        __syncthreads();
        if (tid < 8) {
            const int b = tid;
            float lg[3];
            for (int cc = 0; cc < 3; cc++) {
                float a = b3[cc];
                const float* wr = W3 + cc * 128; const float* x = m2 + b * 128;
                for (int k = 0; k < 128; k++) a += wr[k] * x[k];
                lg[cc] = a;
            }
            float m = fmaxf(lg[0], fmaxf(lg[1], lg[2]));
            float e0 = expf(lg[0] - m), e1 = expf(lg[1] - m), e2 = expf(lg[2] - m);
            float s = e0 + e1 + e2;
            out[b * 3 + 0] = e0 / s;
            out[b * 3 + 1] = e1 / s;
            out[b * 3 + 2] = e2 / s;
        }
    }
}

extern "C" void kernel_launch(void* const* d_in, const int* in_sizes, int n_in,
                              void* d_out, int out_size, void* d_ws, size_t ws_size,
                              hipStream_t stream) {
    const int*   premise    = (const int*)d_in[0];
    const int*   hypothesis = (const int*)d_in[1];
    const float* emb        = (const float*)d_in[2];
    const float* W_ih       = (const float*)d_in[3];
    const float* b_ih       = (const float*)d_in[4];
    const float* W_hh       = (const float*)d_in[5];
    const float* b_hh       = (const float*)d_in[6];
    const float* W_ch       = (const float*)d_in[7];
    const float* b_ch       = (const float*)d_in[8];
    const float* W_cc       = (const float*)d_in[9];
    const float* b_cc       = (const float*)d_in[10];
    const float* W1         = (const float*)d_in[11];
    const float* b1         = (const float*)d_in[12];
    const float* W2         = (const float*)d_in[13];
    const float* b2         = (const float*)d_in[14];
    const float* W3         = (const float*)d_in[15];
    const float* b3         = (const float*)d_in[16];
    float* out = (float*)d_out;
    float* ws  = (float*)d_ws;

    (void)in_sizes; (void)n_in; (void)out_size; (void)ws_size;

    grid_lstm_kernel<<<dim3(256), dim3(256), 0, stream>>>(
        premise, hypothesis, emb, W_ih, b_ih, W_hh, b_hh,
        W_ch, b_ch, W_cc, b_cc, W1, b1, W2, b2, W3, b3, out, ws);
}

// Round 7
// 659.587 us; speedup vs baseline: 5819.4385x; 1.1593x over previous
//
#include <hip/hip_runtime.h>
#include <math.h>

// GridLSTM one-flag-per-cell dataflow, fused f16 weights. V=50000,E=300,H=128,L=32,B=8.
// 256 blocks x 256 threads. bid = c*32 + i (i = grid row, c = t-slice chunk 0..7).
// gates = WU@ho_up + WL@ho_left + (Pproj+b) + Hypproj + upok*bU + lfok*bL
// with WU/WL precomputed f16x2 on device, consumed via v_dot2_f32_f16.
//
// R7 = R6 (656us best) + DRAIN-FREE publish via tagged u64 granules.
//   Hop ledger after R6: compute 1.7 + barriers 0.8 + drain-ack ~1.5 +
//   flag-flight/detect ~2 + data-load ~1.5 + jitter. This round removes the
//   drain RT: data published as u64 {tag<<32|payload} (tag = i*32+j+1, 8B
//   atomic, R1-proven transport); producer fires its per-wave flag WITHOUT
//   vmcnt(0). Consumer keeps the PROVEN throttled flag spin (idle-block poll
//   pressure stays low - R5 lesson), then does the R6-batched load as tagged
//   loads with predicated retry. Flag/store race is closed by tags; since
//   detection lags store-issue by ~2us, expected retries ~= 0.
//   R1's tags failed because its fallback (syncthreads_or -> flag wait ->
//   resweep) made tags additive to the flag path; here they REPLACE the drain.

typedef _Float16 h2 __attribute__((ext_vector_type(2)));
typedef unsigned long long ull;

__device__ __forceinline__ h2 pk_f16(float a, float b) {
    return __builtin_bit_cast(h2, __builtin_amdgcn_cvt_pkrtz(a, b));
}

// ---------------- workspace layout (float words) — total 1,321,984 (<= R1's 5.30MB) ----
#define HYP_OFF   0            // Hypproj [32 j][8 b][1024]            (atomic f32) 1MB
#define WP_OFF    262144       // fused wts packed h2 [1024 g][256]    (atomic u32) 1MB
#define B_OFF     524288       // bU[1024] | bL[1024]
#define INITF_OFF 526336       // InitF [p*4] (1024 floats)
#define WF_OFF    527360       // per-wave flags [((i*8+c)*4+w)*4] (4096 floats)
#define HOT_OFF   531456       // Ho tagged u64 [4 dep][32 j][8 b][128 kk] (1MB)
#define COT_OFF   793600       // Co tagged u64 [4 dep][32 j][8 b][256 t]  (2MB)
#define HOF_OFF   1317888      // final ho(31,31) tagged u64 [8 b][256 t]  (16KB)
// end = 1321984 floats = 5.288 MB

#define BASE 0xAAAAAAAAu

__device__ __forceinline__ float sigm(float x) { return 1.f / (1.f + __expf(-x)); }
__device__ __forceinline__ float tanh_fast(float x) { return 1.f - 2.f / (__expf(2.f * x) + 1.f); }

__device__ __forceinline__ unsigned ld_flag(const unsigned* p) {
    return __hip_atomic_load(p, __ATOMIC_RELAXED, __HIP_MEMORY_SCOPE_AGENT);
}
__device__ __forceinline__ void st_flag(unsigned* p, unsigned v) {
    __hip_atomic_store(p, v, __ATOMIC_RELAXED, __HIP_MEMORY_SCOPE_AGENT);
}
__device__ __forceinline__ float ld_f32(const float* p) {
    unsigned u = __hip_atomic_load((const unsigned*)p, __ATOMIC_RELAXED, __HIP_MEMORY_SCOPE_AGENT);
    return __uint_as_float(u);
}
__device__ __forceinline__ void st_f32(float* p, float v) {
    __hip_atomic_store((unsigned*)p, __float_as_uint(v), __ATOMIC_RELAXED, __HIP_MEMORY_SCOPE_AGENT);
}
__device__ __forceinline__ void st_u32(unsigned* p, unsigned v) {
    __hip_atomic_store(p, v, __ATOMIC_RELAXED, __HIP_MEMORY_SCOPE_AGENT);
}
__device__ __forceinline__ ull ld_u64(const ull* p) {
    return __hip_atomic_load(p, __ATOMIC_RELAXED, __HIP_MEMORY_SCOPE_AGENT);
}
__device__ __forceinline__ void st_u64(ull* p, ull v) {
    __hip_atomic_store(p, v, __ATOMIC_RELAXED, __HIP_MEMORY_SCOPE_AGENT);
}
__device__ __forceinline__ void wait_ge(const unsigned* f, unsigned target) {
    long spins = 0;
    while ((ld_flag(f) - BASE) < target) {
        __builtin_amdgcn_s_sleep(1);
        if (++spins > (1L << 22)) break;   // failsafe: wrong answer > hang
    }
}
__device__ __forceinline__ void drain_vmem() {
    asm volatile("s_waitcnt vmcnt(0)" ::: "memory");
}

__global__ void __launch_bounds__(256, 1) grid_lstm_kernel(
    const int* __restrict__ premise, const int* __restrict__ hypothesis,
    const float* __restrict__ emb,
    const float* __restrict__ W_ih, const float* __restrict__ b_ih,
    const float* __restrict__ W_hh, const float* __restrict__ b_hh,
    const float* __restrict__ W_ch, const float* __restrict__ b_ch,
    const float* __restrict__ W_cc, const float* __restrict__ b_cc,
    const float* __restrict__ W1, const float* __restrict__ b1,
    const float* __restrict__ W2, const float* __restrict__ b2,
    const float* __restrict__ W3, const float* __restrict__ b3,
    float* __restrict__ out, float* __restrict__ ws)
{
    __shared__ h2    hAB[2048];      // f16 [8 b][256 kk]: kk<128 up, kk>=128 left (8KB)
    __shared__ float sCo[2048];      // f32 co_side [8 b][256] (8KB)
    __shared__ float ppL[1024];      // Pproj slice [8 b][128 g], g=(a<<5)|s (4KB)
    __shared__ float red[8448];      // gate partials [256][33] / embs / MLP (33.8KB)
    __shared__ float red2[2304];     // c partials [256][9] (9.2KB)

    const int tid = threadIdx.x;
    const int bid = blockIdx.x;
    const int i   = bid & 31;       // grid row
    const int c   = bid >> 5;       // t-slice chunk

    float*    Hypproj = ws + HYP_OFF;
    unsigned* WP      = (unsigned*)(ws + WP_OFF);
    float*    BU      = ws + B_OFF;
    float*    BL      = ws + B_OFF + 1024;
    unsigned* InitF   = (unsigned*)(ws + INITF_OFF);   // [p*4]
    unsigned* WF      = (unsigned*)(ws + WF_OFF);      // [((i*8+c)*4+w)*4]
    ull*      HoT     = (ull*)(ws + HOT_OFF);          // {tag<<32 | f16x2}
    ull*      CoT     = (ull*)(ws + COT_OFF);          // {tag<<32 | f32}
    ull*      HoF     = (ull*)(ws + HOF_OFF);          // {tag<<32 | f32}

    const int tq = tid & 31, ks = tid >> 5;   // GEMM K-split coords
    const int tl = tid & 31, bb = tid >> 5;   // elementwise coords (t_local, batch)

    // ================= Init A: Pproj (LDS) + Hypproj for this block's gate rows ====
    {
        float* embs = red;   // [2 sides][8][300] = 4800 floats
        for (int idx = tid; idx < 4800; idx += 256) {
            int side = idx / 2400, rem = idx - side * 2400;
            int b = rem / 300, e = rem - b * 300;
            const int* toks = side ? hypothesis : premise;
            embs[idx] = emb[(long)toks[b * 32 + i] * 300 + e];
        }
        __syncthreads();
        #pragma unroll 1
        for (int q = 0; q < 4; q++) {
            const int oo = tid + q * 256;
            const int b = oo >> 7, g = oo & 127;
            const int gr = (g >> 5) * 256 + c * 32 + (g & 31);   // t-sliced gate row
            float accP = b_ih[gr] + b_hh[gr];
            float accH = 0.f;
            const float* wp = W_ih + (long)gr * 600;
            const float* eP = embs + b * 300;
            const float* eH = embs + 2400 + b * 300;
            for (int e = 0; e < 300; e += 4) {
                float4 w1 = *(const float4*)(wp + e);
                float4 w2v = *(const float4*)(wp + 300 + e);
                float4 p4 = *(const float4*)(eP + e);
                float4 h4 = *(const float4*)(eH + e);
                accP += w1.x * p4.x + w1.y * p4.y + w1.z * p4.z + w1.w * p4.w;
                accH += w2v.x * h4.x + w2v.y * h4.y + w2v.z * h4.z + w2v.w * h4.w;
            }
            st_f32(&Hypproj[i * 8192 + b * 1024 + gr], accH);     // cross-block
            ppL[b * 128 + g] = accP;                              // block-local
        }
        __syncthreads();   // embs (red) free
    }

    // ================= Init B: fused weight rows [4*bid, 4*bid+4) =================
    {
        const int tr = tid >> 6, col = (tid & 63) * 4;
        const int r  = bid * 4 + tr;
        float u[4] = {0.f, 0.f, 0.f, 0.f}, l[4] = {0.f, 0.f, 0.f, 0.f};
        const float* whU = W_hh + (long)r * 256;
        const float* whL = whU + 128;
        for (int k = 0; k < 128; k++) {
            const float wu = whU[k], wl = whL[k];
            float4 wc = *(const float4*)(W_ch + (long)k * 256 + col);
            u[0] += wu * wc.x; u[1] += wu * wc.y; u[2] += wu * wc.z; u[3] += wu * wc.w;
            l[0] += wl * wc.x; l[1] += wl * wc.y; l[2] += wl * wc.z; l[3] += wl * wc.w;
        }
        unsigned* wrow = WP + (long)r * 256;
        st_u32(&wrow[col / 2],       __builtin_bit_cast(unsigned, __builtin_amdgcn_cvt_pkrtz(u[0], u[1])));
        st_u32(&wrow[col / 2 + 1],   __builtin_bit_cast(unsigned, __builtin_amdgcn_cvt_pkrtz(u[2], u[3])));
        st_u32(&wrow[128 + col / 2],     __builtin_bit_cast(unsigned, __builtin_amdgcn_cvt_pkrtz(l[0], l[1])));
        st_u32(&wrow[128 + col / 2 + 1], __builtin_bit_cast(unsigned, __builtin_amdgcn_cvt_pkrtz(l[2], l[3])));
        if ((tid & 63) == 0) {   // bias projections for this row
            float su = 0.f, sl = 0.f;
            for (int k = 0; k < 128; k++) { su += whU[k] * b_ch[k]; sl += whL[k] * b_ch[k]; }
            st_f32(&BU[r], su); st_f32(&BL[r], sl);
        }
    }
    drain_vmem();
    __syncthreads();
    if (tid == 0) st_flag(&InitF[bid * 4], BASE + 1u);

    // ---- wait ALL inits (covers every Hypproj row + all fused weights) ----
    wait_ge(&InitF[tid * 4], 1u);
    __syncthreads();

    // ---- load fused weight slice -> registers (f16x2), W_cc slice (fp32) ----
    h2 w[4][32];                  // 128 VGPRs
    #pragma unroll
    for (int a = 0; a < 4; a++) {
        const unsigned* src = WP + (long)(a * 256 + c * 32 + tq) * 256 + ks * 32;
        #pragma unroll
        for (int m = 0; m < 16; m++) {
            ull u2 = ld_u64((const ull*)(src + m * 2));
            w[a][2 * m]     = __builtin_bit_cast(h2, (unsigned)u2);
            w[a][2 * m + 1] = __builtin_bit_cast(h2, (unsigned)(u2 >> 32));
        }
    }
    float4 w3[8];                 // 32 VGPRs: W_cc row (c&3)*32+tq, K-seg ks*32..+32
    {
        const float* wr = W_cc + (long)((c & 3) * 32 + tq) * 256 + ks * 32;
        #pragma unroll
        for (int m = 0; m < 8; m++) w3[m] = *(const float4*)(wr + m * 4);
    }
    float bUv[4], bLv[4];
    #pragma unroll
    for (int a = 0; a < 4; a++) {
        bUv[a] = ld_f32(&BU[a * 256 + c * 32 + tl]);
        bLv[a] = ld_f32(&BL[a * 256 + c * 32 + tl]);
    }

    // ================= Wavefront: row i walks j = 0..31 =================
    #pragma unroll 1
    for (int j = 0; j < 32; j++) {
        const bool upok = (i > 0), lfok = (j > 0);
        const bool cok  = (c < 4) ? upok : lfok;
        const int  jl   = lfok ? (j - 1) : 0;

        const unsigned upTag = (unsigned)((i - 1) * 32 + j + 1);   // tag of cell (i-1,j)
        const unsigned lfTag = (unsigned)(i * 32 + j);             // tag of cell (i,j-1)
        const unsigned coTag = (c < 4) ? upTag : lfTag;

        // ---- fine-grained dependency wait: 60 lanes, one per-wave flag each ----
        // (throttle only; data correctness is carried by the tags below)
        {
            const unsigned* fp = nullptr;
            unsigned tgt = 0;
            if (upok && tid < 32) {
                fp = &WF[(((i - 1) * 8 + (tid >> 2)) * 4 + (tid & 3)) * 4];
                tgt = (unsigned)(j + 1);
            } else if (lfok && tid >= 32 && tid < 60) {
                int s = tid - 32;
                int cc = s >> 2;
                cc += (cc >= c) ? 1 : 0;          // skip self (own data in own LDS path)
                fp = &WF[((i * 8 + cc) * 4 + (s & 3)) * 4];
                tgt = (unsigned)j;
            }
            if (fp) wait_ge(fp, tgt);             // lanes exit individually; up & left concurrent
        }
        __syncthreads();

        // ---- BATCHED tagged loads + predicated retry (expected 1 round) ----
        const ull* HoUpT = HoT + (size_t)(((i - 1) & 3) * 32 + j) * 1024;
        const ull* HoLfT = HoT + (size_t)((i & 3) * 32 + jl) * 1024;
        const ull* CoST  = (c < 4)
            ? CoT + (size_t)(((i - 1) & 3) * 32 + j) * 2048
            : CoT + (size_t)((i & 3) * 32 + jl) * 2048;
        const int hi = tid >> 7, kk = tid & 127;   // b = 2r + hi, kk fixed across r

        float hyv[4];
        #pragma unroll
        for (int a = 0; a < 4; a++)
            hyv[a] = ld_f32(&Hypproj[j * 8192 + bb * 1024 + a * 256 + c * 32 + tl]);

        ull uv[4] = {0, 0, 0, 0}, lv[4] = {0, 0, 0, 0};
        ull cv[8] = {0, 0, 0, 0, 0, 0, 0, 0};
        unsigned pend = (upok ? 0x000Fu : 0u) | (lfok ? 0x00F0u : 0u) | (cok ? 0xFF00u : 0u);
        long spins = 0;
        while (pend) {
            #pragma unroll
            for (int r = 0; r < 4; r++) {
                if (pend & (1u << r))        uv[r] = ld_u64(HoUpT + (2 * r + hi) * 128 + kk);
                if (pend & (0x10u << r))     lv[r] = ld_u64(HoLfT + (2 * r + hi) * 128 + kk);
                if (pend & (0x100u << 2*r))  cv[2*r]   = ld_u64(CoST + (2 * r + hi) * 256 + 2 * kk);
                if (pend & (0x200u << 2*r))  cv[2*r+1] = ld_u64(CoST + (2 * r + hi) * 256 + 2 * kk + 1);
            }
            #pragma unroll
            for (int r = 0; r < 4; r++) {
                if ((pend & (1u << r))       && (unsigned)(uv[r] >> 32) == upTag)      pend &= ~(1u << r);
                if ((pend & (0x10u << r))    && (unsigned)(lv[r] >> 32) == lfTag)      pend &= ~(0x10u << r);
                if ((pend & (0x100u << 2*r)) && (unsigned)(cv[2*r] >> 32) == coTag)    pend &= ~(0x100u << 2*r);
                if ((pend & (0x200u << 2*r)) && (unsigned)(cv[2*r+1] >> 32) == coTag)  pend &= ~(0x200u << 2*r);
            }
            if (pend) {
                __builtin_amdgcn_s_sleep(1);
                if (++spins > (1L << 22)) break;   // failsafe: wrong answer > hang
            }
        }
        __builtin_amdgcn_sched_barrier(0);   // keep loads/checks before LDS writes
        #pragma unroll
        for (int r = 0; r < 4; r++) {
            const int b = 2 * r + hi;
            hAB[b * 256 + kk]       = __builtin_bit_cast(h2, (unsigned)uv[r]);   // 0u == (0,0)
            hAB[b * 256 + 128 + kk] = __builtin_bit_cast(h2, (unsigned)lv[r]);
            sCo[b * 256 + 2 * kk]     = __uint_as_float((unsigned)cv[2*r]);
            sCo[b * 256 + 2 * kk + 1] = __uint_as_float((unsigned)cv[2*r+1]);
        }
        __syncthreads();

        // ---- fused gates GEMM (f16 dot2) + c-path (fp32) ----
        float acc[4][8], a3[8];
        #pragma unroll
        for (int a = 0; a < 4; a++)
            #pragma unroll
            for (int b = 0; b < 8; b++) acc[a][b] = 0.f;
        #pragma unroll
        for (int b = 0; b < 8; b++) a3[b] = 0.f;
        #pragma unroll
        for (int b = 0; b < 8; b++) {
            const h2*    hb = hAB + b * 256 + ks * 32;
            const float* cb = sCo + b * 256 + ks * 32;
            #pragma unroll
            for (int m4 = 0; m4 < 8; m4++) {
                uint4 hu = *(const uint4*)(hb + m4 * 4);
                h2 h0 = __builtin_bit_cast(h2, hu.x);
                h2 h1 = __builtin_bit_cast(h2, hu.y);
                h2 h2v = __builtin_bit_cast(h2, hu.z);
                h2 h3 = __builtin_bit_cast(h2, hu.w);
                #pragma unroll
                for (int a = 0; a < 4; a++) {
                    acc[a][b] = __builtin_amdgcn_fdot2(w[a][m4 * 4],     h0,  acc[a][b], false);
                    acc[a][b] = __builtin_amdgcn_fdot2(w[a][m4 * 4 + 1], h1,  acc[a][b], false);
                    acc[a][b] = __builtin_amdgcn_fdot2(w[a][m4 * 4 + 2], h2v, acc[a][b], false);
                    acc[a][b] = __builtin_amdgcn_fdot2(w[a][m4 * 4 + 3], h3,  acc[a][b], false);
                }
                float4 cv4 = *(const float4*)(cb + m4 * 4);
                a3[b] += w3[m4].x * cv4.x + w3[m4].y * cv4.y + w3[m4].z * cv4.z + w3[m4].w * cv4.w;
            }
        }
        #pragma unroll
        for (int a = 0; a < 4; a++)
            #pragma unroll
            for (int b = 0; b < 8; b++) red[tid * 33 + a * 8 + b] = acc[a][b];
        #pragma unroll
        for (int b = 0; b < 8; b++) red2[tid * 9 + b] = a3[b];
        __syncthreads();

        // ---- elementwise (block-local) + DRAIN-FREE tagged publish ----
        {
            float g4[4];
            #pragma unroll
            for (int a = 0; a < 4; a++) {
                float s = 0.f;
                #pragma unroll
                for (int k = 0; k < 8; k++)
                    s += red[(k * 32 + tl) * 33 + a * 8 + bb];
                s += ppL[bb * 128 + a * 32 + tl] + hyv[a];
                if (upok) s += bUv[a];
                if (lfok) s += bLv[a];
                g4[a] = s;
            }
            float ci = 0.f;
            #pragma unroll
            for (int k = 0; k < 8; k++) ci += red2[(k * 32 + tl) * 9 + bb];
            if (cok) ci += b_cc[(c & 3) * 32 + tl];
            const float cnew = sigm(g4[1]) * ci + sigm(g4[0]) * tanh_fast(g4[2]);
            const float hnew = sigm(g4[3]) * tanh_fast(cnew);

            const unsigned myTag = (unsigned)(i * 32 + j + 1);
            const ull tagHi = ((ull)myTag) << 32;
            const int slot = (i & 3) * 32 + j;

            st_u64(&CoT[(size_t)slot * 2048 + bb * 256 + c * 32 + tl],
                   tagHi | (ull)__float_as_uint(cnew));
            const float hOdd = __shfl_xor(hnew, 1);
            if ((tl & 1) == 0)
                st_u64(&HoT[(size_t)slot * 1024 + bb * 128 + c * 16 + (tl >> 1)],
                       tagHi | (ull)__builtin_bit_cast(unsigned, pk_f16(hnew, hOdd)));
            if (i == 31 && j == 31)
                st_u64(&HoF[bb * 256 + c * 32 + tl],
                       tagHi | (ull)__float_as_uint(hnew));   // full-precision corner
        }
        // NO drain: tags carry data correctness; flag is issue-ordered only.
        if ((tid & 63) == 0)
            st_flag(&WF[((i * 8 + c) * 4 + (tid >> 6)) * 4], BASE + (unsigned)(j + 1));
    }

    // ================= Final: condense ho(31,31) + MLP + softmax (bid 31) ==========
    if (bid == 31) {
        if (tid < 32)
            wait_ge(&WF[((31 * 8 + (tid >> 2)) * 4 + (tid & 3)) * 4], 32u);
        __syncthreads();
        const unsigned fTag = 1024u;   // 31*32 + 31 + 1
        float hov[8] = {0.f, 0.f, 0.f, 0.f, 0.f, 0.f, 0.f, 0.f};
        unsigned pf = 0xFFu;
        long spins = 0;
        while (pf) {
            ull tv[8];
            #pragma unroll
            for (int r = 0; r < 8; r++)
                if (pf & (1u << r)) tv[r] = ld_u64(HoF + r * 256 + tid);
            #pragma unroll
            for (int r = 0; r < 8; r++)
                if ((pf & (1u << r)) && (unsigned)(tv[r] >> 32) == fTag) {
                    hov[r] = __uint_as_float((unsigned)tv[r]);
                    pf &= ~(1u << r);
                }
            if (pf) {
                __builtin_amdgcn_s_sleep(1);
                if (++spins > (1L << 22)) break;   // failsafe
            }
        }
        #pragma unroll
        for (int r = 0; r < 8; r++) sCo[r * 256 + tid] = hov[r];
        __syncthreads();
        // condense: hcond[b][o] = b_ch[o] + W_ch[o,:] @ ho[b,:]
        #pragma unroll 1
        for (int q = 0; q < 4; q++) {
            const int oo = tid + q * 256;
            const int b = oo >> 7, o = oo & 127;
            float a = b_ch[o];
            const float* wr = W_ch + (long)o * 256;
            const float* x = sCo + b * 256;
            for (int k = 0; k < 256; k += 4) {
                float4 wv = *(const float4*)(wr + k);
                float4 xv = *(const float4*)(x + k);
                a += wv.x * xv.x + wv.y * xv.y + wv.z * xv.z + wv.w * xv.w;
            }
            ppL[b * 128 + o] = a;
        }
        __syncthreads();
        float* m1 = red;          // [8][128]
        float* m2 = red + 1024;   // [8][128]
        for (int idx = tid; idx < 1024; idx += 256) {
            int b = idx >> 7, o = idx & 127;
            float a = b1[o];
            const float* wr = W1 + o * 128; const float* x = ppL + b * 128;
            for (int k = 0; k < 128; k++) a += wr[k] * x[k];
            m1[idx] = fmaxf(a, 0.f);
        }
        __syncthreads();
        for (int idx = tid; idx < 1024; idx += 256) {
            int b = idx >> 7, o = idx & 127;
            float a = b2[o];
            const float* wr = W2 + o * 128; const float* x = m1 + b * 128;
            for (int k = 0; k < 128; k++) a += wr[k] * x[k];
            m2[idx] = fmaxf(a, 0.f);
        }
        __syncthreads();
        if (tid < 8) {
            const int b = tid;
            float lg[3];
            for (int cc = 0; cc < 3; cc++) {
                float a = b3[cc];
                const float* wr = W3 + cc * 128; const float* x = m2 + b * 128;
                for (int k = 0; k < 128; k++) a += wr[k] * x[k];
                lg[cc] = a;
            }
            float m = fmaxf(lg[0], fmaxf(lg[1], lg[2]));
            float e0 = expf(lg[0] - m), e1 = expf(lg[1] - m), e2 = expf(lg[2] - m);
            float s = e0 + e1 + e2;
            out[b * 3 + 0] = e0 / s;
            out[b * 3 + 1] = e1 / s;
            out[b * 3 + 2] = e2 / s;
        }
    }
}

extern "C" void kernel_launch(void* const* d_in, const int* in_sizes, int n_in,
                              void* d_out, int out_size, void* d_ws, size_t ws_size,
                              hipStream_t stream) {
    const int*   premise    = (const int*)d_in[0];
    const int*   hypothesis = (const int*)d_in[1];
    const float* emb        = (const float*)d_in[2];
    const float* W_ih       = (const float*)d_in[3];
    const float* b_ih       = (const float*)d_in[4];
    const float* W_hh       = (const float*)d_in[5];
    const float* b_hh       = (const float*)d_in[6];
    const float* W_ch       = (const float*)d_in[7];
    const float* b_ch       = (const float*)d_in[8];
    const float* W_cc       = (const float*)d_in[9];
    const float* b_cc       = (const float*)d_in[10];
    const float* W1         = (const float*)d_in[11];
    const float* b1         = (const float*)d_in[12];
    const float* W2         = (const float*)d_in[13];
    const float* b2         = (const float*)d_in[14];
    const float* W3         = (const float*)d_in[15];
    const float* b3         = (const float*)d_in[16];
    float* out = (float*)d_out;
    float* ws  = (float*)d_ws;

    (void)in_sizes; (void)n_in; (void)out_size; (void)ws_size;

    grid_lstm_kernel<<<dim3(256), dim3(256), 0, stream>>>(
        premise, hypothesis, emb, W_ih, b_ih, W_hh, b_hh,
        W_ch, b_ch, W_cc, b_cc, W1, b1, W2, b2, W3, b3, out, ws);
}